// Round 1
// baseline (752.168 us; speedup 1.0000x reference)
//
#include <hip/hip_runtime.h>
#include <hip/hip_bf16.h>

#define NB 2
#define LSEQ 4096
#define DIN 4384
#define DINNER 2048
#define DSTATE 128
#define CONVD 2304
#define HD 64
#define NH 32
#define CK 256
#define NCH 16

__device__ __forceinline__ float bf2f(unsigned short u){ return __uint_as_float(((unsigned int)u)<<16); }
__device__ __forceinline__ unsigned short f2bf(float f){
  unsigned int u = __float_as_uint(f);
  unsigned int r = (u + 0x7fffu + ((u>>16)&1u)) >> 16;
  return (unsigned short)r;
}
__device__ __forceinline__ float blo(unsigned int u){ return __uint_as_float(u<<16); }
__device__ __forceinline__ float bhi(unsigned int u){ return __uint_as_float(u & 0xffff0000u); }
__device__ __forceinline__ void up8(uint4 v, float* f){
  f[0]=blo(v.x); f[1]=bhi(v.x); f[2]=blo(v.y); f[3]=bhi(v.y);
  f[4]=blo(v.z); f[5]=bhi(v.z); f[6]=blo(v.w); f[7]=bhi(v.w);
}

// ---------------- K1: causal conv + silu -> xconv (bf16) ----------------
__global__ __launch_bounds__(256) void k_conv(const float* __restrict__ zx,
    const float* __restrict__ cw, const float* __restrict__ cb,
    unsigned short* __restrict__ xconv)
{
  int idx = blockIdx.x*256 + threadIdx.x;   // NB*LSEQ*CONVD total (exact)
  int c = idx % CONVD;
  int row = idx / CONVD;                    // b*LSEQ + l
  int b = row / LSEQ;
  int l = row % LSEQ;
  float acc = cb[c];
  #pragma unroll
  for (int k=0;k<4;k++){
    int ls = l + k - 3;
    if (ls >= 0) acc += cw[c*4+k] * zx[(size_t)(b*LSEQ + ls)*DIN + DINNER + c];
  }
  float s = acc / (1.f + __expf(-acc));
  xconv[(size_t)row*CONVD + c] = f2bf(s);
}

// ---------------- K1b: dt = clip(softplus(raw+bias),0,100) ----------------
__global__ __launch_bounds__(256) void k_dt(const float* __restrict__ zx,
    const float* __restrict__ dtb, float* __restrict__ dtv)
{
  int idx = blockIdx.x*256 + threadIdx.x;   // NB*LSEQ*NH
  int h = idx & 31;
  int row = idx >> 5;
  float x = zx[(size_t)row*DIN + DINNER + CONVD + h] + dtb[h];
  float sp = (x > 20.f) ? x : log1pf(__expf(x));
  sp = fminf(sp, 100.f);
  dtv[idx] = sp;
}

// ---------------- K2a: Gt[s][l] = sum_n C[l,n]*B[s,n], per (b,chunk) ----------------
__global__ __launch_bounds__(256) void k_gmat(const unsigned short* __restrict__ xconv,
    float* __restrict__ gt)
{
  int bid = blockIdx.x;                     // NB*NCH*16
  int st = bid & 3, lt = (bid>>2)&3, c = (bid>>4)&15, b = bid>>8;
  if (st > lt) return;                      // only lower-tri tiles needed
  __shared__ unsigned short sB[64][130];
  __shared__ unsigned short sC[64][130];
  int t = threadIdx.x;
  #pragma unroll
  for (int k=0;k<32;k++){
    int idx = t + 256*k;                    // 64*128 elems
    int r = idx >> 7, col = idx & 127;
    sB[r][col] = xconv[(size_t)(b*LSEQ + c*CK + st*64 + r)*CONVD + DINNER + col];
    sC[r][col] = xconv[(size_t)(b*LSEQ + c*CK + lt*64 + r)*CONVD + DINNER + DSTATE + col];
  }
  __syncthreads();
  int i = t >> 4, j = t & 15;
  float acc[4][4];
  #pragma unroll
  for (int k=0;k<4;k++)
    #pragma unroll
    for (int m=0;m<4;m++) acc[k][m] = 0.f;
  for (int n=0; n<128; n+=2){
    unsigned int bu[4], cu[4];
    #pragma unroll
    for (int k=0;k<4;k++){
      bu[k] = *(const unsigned int*)&sB[4*i+k][n];
      cu[k] = *(const unsigned int*)&sC[4*j+k][n];
    }
    #pragma unroll
    for (int k=0;k<4;k++){
      float b0 = blo(bu[k]), b1 = bhi(bu[k]);
      #pragma unroll
      for (int m=0;m<4;m++)
        acc[k][m] += b0*blo(cu[m]) + b1*bhi(cu[m]);
    }
  }
  float* gbase = gt + (size_t)(b*NCH + c)*CK*CK;
  #pragma unroll
  for (int k=0;k<4;k++){
    int s = st*64 + 4*i + k;
    *(float4*)&gbase[(size_t)s*CK + lt*64 + 4*j] =
        make_float4(acc[k][0], acc[k][1], acc[k][2], acc[k][3]);
  }
}

// ---------------- K2b: acs + states + Y_diag, per (b,chunk,h) ----------------
__global__ __launch_bounds__(256) void k_chunk(const unsigned short* __restrict__ xconv,
   const float* __restrict__ dtv, const float* __restrict__ alog,
   const float* __restrict__ gt, unsigned short* __restrict__ states,
   float* __restrict__ acsg, float* __restrict__ out)
{
  int bid = blockIdx.x;                     // NB*NCH*NH
  int h = bid & 31, c = (bid>>5)&15, b = bid>>9;
  int t = threadIdx.x;
  __shared__ float s_acs[CK];
  __shared__ float s_w[CK];
  __shared__ float s_dt[CK];
  __shared__ unsigned short s_xs[CK][HD];

  int lg = c*CK + t;
  float dtl = dtv[(size_t)(b*LSEQ + lg)*NH + h];
  float Ah = -__expf(alog[h]);
  float a = dtl * Ah;
  s_dt[t] = dtl;
  s_acs[t] = a;
  __syncthreads();
  #pragma unroll
  for (int off=1; off<256; off<<=1){
    float v = (t>=off) ? s_acs[t-off] : 0.f;
    __syncthreads();
    s_acs[t] += v;
    __syncthreads();
  }
  float alast = s_acs[CK-1];
  s_w[t] = __expf(alast - s_acs[t]);
  acsg[((size_t)(b*NCH + c)*NH + h)*CK + t] = s_acs[t];
  // stage dt-scaled x in LDS (bf16)
  #pragma unroll 4
  for (int k=0;k<64;k++){
    int idx = t + 256*k;
    int l = idx >> 6, p = idx & 63;
    float x = bf2f(xconv[(size_t)(b*LSEQ + c*CK + l)*CONVD + h*HD + p]);
    s_xs[l][p] = f2bf(x * s_dt[l]);
  }
  __syncthreads();

  // ---- phase 1: states[p][n] = sum_l B[l,n] * w[l] * xs[l,p] ----
  int i = t >> 4, j = t & 15;
  int p0 = 4*i, n0 = 8*j;
  float accs[4][8];
  #pragma unroll
  for (int k=0;k<4;k++)
    #pragma unroll
    for (int m=0;m<8;m++) accs[k][m]=0.f;
  const unsigned short* bptr = xconv + (size_t)(b*LSEQ + c*CK)*CONVD + DINNER + n0;
  #pragma unroll 2
  for (int l=0; l<CK; ++l){
    float w = s_w[l];
    uint4 bv = *(const uint4*)(bptr + (size_t)l*CONVD);
    uint2 xv = *(const uint2*)&s_xs[l][p0];
    float xw[4] = { blo(xv.x)*w, bhi(xv.x)*w, blo(xv.y)*w, bhi(xv.y)*w };
    float bn[8];
    up8(bv, bn);
    #pragma unroll
    for (int k=0;k<4;k++)
      #pragma unroll
      for (int m=0;m<8;m++)
        accs[k][m] += xw[k]*bn[m];
  }
  size_t sbase = ((size_t)((b*NCH + c)*NH + h))*HD*DSTATE;
  #pragma unroll
  for (int k=0;k<4;k++){
    uint4 pk;
    pk.x = (unsigned)f2bf(accs[k][0]) | ((unsigned)f2bf(accs[k][1])<<16);
    pk.y = (unsigned)f2bf(accs[k][2]) | ((unsigned)f2bf(accs[k][3])<<16);
    pk.z = (unsigned)f2bf(accs[k][4]) | ((unsigned)f2bf(accs[k][5])<<16);
    pk.w = (unsigned)f2bf(accs[k][6]) | ((unsigned)f2bf(accs[k][7])<<16);
    *(uint4*)&states[sbase + (size_t)(p0+k)*DSTATE + n0] = pk;
  }

  // ---- phase 2: Y_diag[l][p] = sum_{s<=l} Gt[s][l]*exp(acs_l-acs_s)*xs[s][p] ----
  float accy[64];
  #pragma unroll
  for (int q=0;q<64;q++) accy[q]=0.f;
  int l = t;
  float acs_l = s_acs[l];
  const float* gtp = gt + (size_t)(b*NCH + c)*CK*CK + l;
  int smax = t | 63;                        // wave-uniform bound
  for (int s=0; s<=smax; ++s){
    float g = gtp[(size_t)s*CK];
    float coef = (s <= l) ? g * __expf(acs_l - s_acs[s]) : 0.f;
    const uint4* xrow = (const uint4*)&s_xs[s][0];
    #pragma unroll
    for (int q=0;q<8;q++){
      uint4 v = xrow[q];
      accy[q*8+0] += coef*blo(v.x);
      accy[q*8+1] += coef*bhi(v.x);
      accy[q*8+2] += coef*blo(v.y);
      accy[q*8+3] += coef*bhi(v.y);
      accy[q*8+4] += coef*blo(v.z);
      accy[q*8+5] += coef*bhi(v.z);
      accy[q*8+6] += coef*blo(v.w);
      accy[q*8+7] += coef*bhi(v.w);
    }
  }
  float* orow = out + (size_t)(b*LSEQ + c*CK + l)*DINNER + h*HD;
  #pragma unroll
  for (int q=0;q<16;q++)
    *(float4*)&orow[4*q] = make_float4(accy[4*q],accy[4*q+1],accy[4*q+2],accy[4*q+3]);
}

// ---------------- K3: inter-chunk state scan (in-place states -> prev_states) ----------------
__global__ __launch_bounds__(256) void k_scan(unsigned short* __restrict__ states,
    const float* __restrict__ acsg)
{
  int bid = blockIdx.x;                     // NB*NH
  int h = bid & 31, b = bid >> 5;
  int t = threadIdx.x;
  float carry[32];
  #pragma unroll
  for (int r=0;r<32;r++) carry[r]=0.f;
  for (int c=0;c<NCH;c++){
    float cs = acsg[((size_t)(b*NCH + c)*NH + h)*CK + (CK-1)];
    float dec = __expf(cs);
    size_t base = ((size_t)((b*NCH + c)*NH + h))*HD*DSTATE;
    #pragma unroll
    for (int r=0;r<32;r++){
      size_t idx = base + t + 256*r;
      float cur = bf2f(states[idx]);
      states[idx] = f2bf(carry[r]);
      carry[r] = dec*carry[r] + cur;
    }
  }
}

// ---------------- K4: Y_off += exp(acs_l) * C_l . prev_state ----------------
__global__ __launch_bounds__(256) void k_yoff(const unsigned short* __restrict__ xconv,
  const unsigned short* __restrict__ states, const float* __restrict__ acsg,
  float* __restrict__ out)
{
  int bid = blockIdx.x;                     // NB*NCH*NH
  int h = bid & 31, c = (bid>>5)&15, b = bid>>9;
  int t = threadIdx.x;
  __shared__ unsigned short psT[128][72];   // prev_state transposed [n][p]
  __shared__ unsigned short sC[64][130];
  size_t sbase = ((size_t)((b*NCH + c)*NH + h))*HD*DSTATE;
  #pragma unroll
  for (int k=0;k<32;k++){
    int idx = t + 256*k;
    int p = idx >> 7, n = idx & 127;
    psT[n][p] = states[sbase + idx];
  }
  for (int lt=0; lt<4; ++lt){
    __syncthreads();
    #pragma unroll
    for (int k=0;k<32;k++){
      int idx = t + 256*k;
      int r = idx >> 7, col = idx & 127;
      sC[r][col] = xconv[(size_t)(b*LSEQ + c*CK + lt*64 + r)*CONVD + DINNER + DSTATE + col];
    }
    __syncthreads();
    int lq = t >> 2, pq = t & 3, p0 = pq*16;
    float acc[16];
    #pragma unroll
    for (int e=0;e<16;e++) acc[e]=0.f;
    for (int n=0;n<128;n+=2){
      unsigned int cu = *(const unsigned int*)&sC[lq][n];
      float c0 = blo(cu), c1 = bhi(cu);
      const uint4* pr0 = (const uint4*)&psT[n][p0];
      const uint4* pr1 = (const uint4*)&psT[n+1][p0];
      uint4 a0 = pr0[0], a1 = pr0[1], b0q = pr1[0], b1q = pr1[1];
      float fa[16], fb[16];
      up8(a0, fa); up8(a1, fa+8); up8(b0q, fb); up8(b1q, fb+8);
      #pragma unroll
      for (int e=0;e<16;e++) acc[e] += c0*fa[e] + c1*fb[e];
    }
    int l = lt*64 + lq;
    float el = __expf(acsg[((size_t)(b*NCH + c)*NH + h)*CK + l]);
    float* orow = out + (size_t)(b*LSEQ + c*CK + l)*DINNER + h*HD + p0;
    #pragma unroll
    for (int q=0;q<4;q++){
      float4 cur = *(float4*)&orow[4*q];
      cur.x += el*acc[4*q+0];
      cur.y += el*acc[4*q+1];
      cur.z += el*acc[4*q+2];
      cur.w += el*acc[4*q+3];
      *(float4*)&orow[4*q] = cur;
    }
  }
}

// ---------------- K5: + D*x, silu(z) gate, RMSNorm ----------------
__global__ __launch_bounds__(256) void k_final(const float* __restrict__ zx,
  const unsigned short* __restrict__ xconv, const float* __restrict__ dpar,
  const float* __restrict__ nw, float* __restrict__ out)
{
  int row = blockIdx.x;                     // b*LSEQ + l
  int t = threadIdx.x;
  float* orow = out + (size_t)row*DINNER;
  const float* zrow = zx + (size_t)row*DIN;
  const unsigned short* xrow = xconv + (size_t)row*CONVD;
  float vals[8];
  float ss = 0.f;
  #pragma unroll
  for (int k=0;k<2;k++){
    int i4 = t + 256*k;
    float4 y4 = *(const float4*)&orow[4*i4];
    float yv[4] = {y4.x, y4.y, y4.z, y4.w};
    #pragma unroll
    for (int e=0;e<4;e++){
      int d = 4*i4 + e;
      int hh = d >> 6;
      float x = bf2f(xrow[d]);
      float y = yv[e] + x*dpar[hh];
      float z = zrow[d];
      y *= z / (1.f + __expf(-z));
      vals[4*k+e] = y;
      ss += y*y;
    }
  }
  #pragma unroll
  for (int off=1; off<64; off<<=1) ss += __shfl_xor(ss, off, 64);
  __shared__ float red[4];
  if ((t & 63) == 0) red[t>>6] = ss;
  __syncthreads();
  float tot = red[0]+red[1]+red[2]+red[3];
  float rms = rsqrtf(tot * (1.f/(float)DINNER) + 1e-5f);
  #pragma unroll
  for (int k=0;k<2;k++){
    int i4 = t + 256*k;
    float4 w4 = *(const float4*)&nw[4*i4];
    float4 o;
    o.x = vals[4*k+0]*rms*w4.x;
    o.y = vals[4*k+1]*rms*w4.y;
    o.z = vals[4*k+2]*rms*w4.z;
    o.w = vals[4*k+3]*rms*w4.w;
    *(float4*)&orow[4*i4] = o;
  }
}

extern "C" void kernel_launch(void* const* d_in, const int* in_sizes, int n_in,
                              void* d_out, int out_size, void* d_ws, size_t ws_size,
                              hipStream_t stream)
{
  const float* zx   = (const float*)d_in[0];
  const float* cw   = (const float*)d_in[1];
  const float* cb   = (const float*)d_in[2];
  const float* dtb  = (const float*)d_in[3];
  const float* alog = (const float*)d_in[4];
  const float* dpar = (const float*)d_in[5];
  const float* nw   = (const float*)d_in[6];
  float* out = (float*)d_out;
  char* ws = (char*)d_ws;

  // ws layout (bytes):
  unsigned short* xconv  = (unsigned short*)(ws);             // 37,748,736
  float*          dtv    = (float*)(ws + 37748736);           //  1,048,576
  float*          acsg   = (float*)(ws + 38797312);           //  1,048,576
  unsigned short* states = (unsigned short*)(ws + 39845888);  // 16,777,216
  float*          gt     = (float*)(ws + 56623104);           //  8,388,608
  // total 65,011,712 bytes

  hipLaunchKernelGGL(k_conv,  dim3(73728), dim3(256), 0, stream, zx, cw, cb, xconv);
  hipLaunchKernelGGL(k_dt,    dim3(1024),  dim3(256), 0, stream, zx, dtb, dtv);
  hipLaunchKernelGGL(k_gmat,  dim3(NB*NCH*16), dim3(256), 0, stream, xconv, gt);
  hipLaunchKernelGGL(k_chunk, dim3(NB*NCH*NH), dim3(256), 0, stream, xconv, dtv, alog, gt, states, acsg, out);
  hipLaunchKernelGGL(k_scan,  dim3(NB*NH),  dim3(256), 0, stream, states, acsg);
  hipLaunchKernelGGL(k_yoff,  dim3(NB*NCH*NH), dim3(256), 0, stream, xconv, states, acsg, out);
  hipLaunchKernelGGL(k_final, dim3(NB*LSEQ), dim3(256), 0, stream, zx, xconv, dpar, nw, out);
}

// Round 2
// 463.962 us; speedup vs baseline: 1.6212x; 1.6212x over previous
//
#include <hip/hip_runtime.h>
#include <hip/hip_bf16.h>

#define NB 2
#define LSEQ 4096
#define DIN 4384
#define DINNER 2048
#define DSTATE 128
#define CONVD 2304
#define HD 64
#define NH 32
#define CK 256
#define NCH 16

typedef __attribute__((ext_vector_type(8))) short bfrag;
typedef __attribute__((ext_vector_type(4))) float ffrag;

__device__ __forceinline__ float bf2f(unsigned short u){ return __uint_as_float(((unsigned int)u)<<16); }
__device__ __forceinline__ unsigned short f2bf(float f){
  unsigned int u = __float_as_uint(f);
  unsigned int r = (u + 0x7fffu + ((u>>16)&1u)) >> 16;
  return (unsigned short)r;
}
__device__ __forceinline__ bfrag pack8(const float* f){
  bfrag r;
  #pragma unroll
  for (int i=0;i<8;i++) r[i] = (short)f2bf(f[i]);
  return r;
}

// ---------------- K1: causal conv + silu -> xconv (bf16) ----------------
__global__ __launch_bounds__(256) void k_conv(const float* __restrict__ zx,
    const float* __restrict__ cw, const float* __restrict__ cb,
    unsigned short* __restrict__ xconv)
{
  int idx = blockIdx.x*256 + threadIdx.x;   // NB*LSEQ*CONVD total (exact)
  int c = idx % CONVD;
  int row = idx / CONVD;                    // b*LSEQ + l
  int b = row / LSEQ;
  int l = row % LSEQ;
  float acc = cb[c];
  #pragma unroll
  for (int k=0;k<4;k++){
    int ls = l + k - 3;
    if (ls >= 0) acc += cw[c*4+k] * zx[(size_t)(b*LSEQ + ls)*DIN + DINNER + c];
  }
  float s = acc / (1.f + __expf(-acc));
  xconv[(size_t)row*CONVD + c] = f2bf(s);
}

// ---------------- K1b: dt = clip(softplus(raw+bias),0,100), layout [b][h][L] ----------------
__global__ __launch_bounds__(256) void k_dt(const float* __restrict__ zx,
    const float* __restrict__ dtb, float* __restrict__ dtv)
{
  int idx = blockIdx.x*256 + threadIdx.x;   // NB*NH*LSEQ
  int l = idx & (LSEQ-1);
  int bh = idx >> 12;
  int h = bh & 31, b = bh >> 5;
  float x = zx[(size_t)(b*LSEQ + l)*DIN + DINNER + CONVD + h] + dtb[h];
  float sp = (x > 20.f) ? x : log1pf(__expf(x));
  dtv[idx] = fminf(sp, 100.f);
}

// ---------------- K1c: transpose B slice -> BtG[b][n][L] (bf16) ----------------
__global__ __launch_bounds__(256) void k_tr(const unsigned short* __restrict__ xconv,
    unsigned short* __restrict__ btg)
{
  __shared__ unsigned short sT[128][72];
  int bid = blockIdx.x;                     // b*64 + tile
  int b = bid >> 6, tile = bid & 63;
  int l0 = tile * 64;
  int t = threadIdx.x;
  #pragma unroll
  for (int k=0;k<32;k++){
    int idx = 256*k + t;
    int l = idx >> 7, n = idx & 127;
    sT[n][l] = xconv[(size_t)(b*LSEQ + l0 + l)*CONVD + DINNER + n];
  }
  __syncthreads();
  #pragma unroll
  for (int k=0;k<32;k++){
    int idx = 256*k + t;
    int n = idx >> 6, l = idx & 63;
    btg[(size_t)(b*DSTATE + n)*LSEQ + l0 + l] = sT[n][l];
  }
}

// ---------------- K2a (MFMA): G[l][s] = sum_n C[l,n]*B[s,n], bf16 l-major ----------------
__global__ __launch_bounds__(256) void k_gmat(const unsigned short* __restrict__ xconv,
    unsigned short* __restrict__ G)
{
  int bid = blockIdx.x;                     // NB*NCH*16
  int st = bid & 3, lt = (bid>>2)&3, c = (bid>>4)&15, b = bid>>8;
  if (st > lt) return;                      // only lower-tri tiles needed
  int t = threadIdx.x, lane = t & 63, wv = t >> 6;
  int cq = lane & 15, g = lane >> 4;
  const unsigned short* base = xconv + (size_t)(b*LSEQ + c*CK)*CONVD;
  ffrag acc[4];
  #pragma unroll
  for (int ss=0; ss<4; ++ss){ acc[ss][0]=0.f; acc[ss][1]=0.f; acc[ss][2]=0.f; acc[ss][3]=0.f; }
  #pragma unroll
  for (int ks=0; ks<4; ++ks){
    int nb = 32*ks + 8*g;
    int l = lt*64 + 16*wv + cq;
    bfrag afr = *(const bfrag*)(base + (size_t)l*CONVD + DINNER + DSTATE + nb);
    #pragma unroll
    for (int ss=0; ss<4; ++ss){
      int s = st*64 + 16*ss + cq;
      bfrag bfr = *(const bfrag*)(base + (size_t)s*CONVD + DINNER + nb);
      acc[ss] = __builtin_amdgcn_mfma_f32_16x16x32_bf16(afr, bfr, acc[ss], 0,0,0);
    }
  }
  unsigned short* gp = G + (size_t)(b*NCH + c)*CK*CK;
  #pragma unroll
  for (int ss=0; ss<4; ++ss)
    #pragma unroll
    for (int j=0; j<4; ++j){
      int l = lt*64 + 16*wv + 4*g + j, s = st*64 + 16*ss + cq;
      gp[(size_t)l*CK + s] = f2bf(acc[ss][j]);
    }
}

// ---------------- K2b: acs + states(MFMA) + Y_diag(MFMA), per (b,chunk,h) ----------------
__global__ __launch_bounds__(256) void k_chunk(const unsigned short* __restrict__ xconv,
   const unsigned short* __restrict__ btg,
   const float* __restrict__ dtv, const float* __restrict__ alog,
   const unsigned short* __restrict__ G,
   unsigned short* __restrict__ states,
   float* __restrict__ acsg2, float* __restrict__ out)
{
  int bid = blockIdx.x;                     // NB*NCH*NH
  int h = bid & 31, c = (bid>>5)&15, b = bid>>9;
  int t = threadIdx.x, lane = t & 63, wv = t >> 6;
  int cq = lane & 15, g = lane >> 4;
  __shared__ float s_acs2[CK];
  __shared__ float s_w[CK];
  __shared__ float s_dt[CK];
  __shared__ unsigned short s_xsT[64][256];  // [p][l], l XOR-swizzled by ((p&7)<<3)

  const float LOG2E = 1.44269504088896340736f;
  float dtl = dtv[(size_t)(b*NH + h)*LSEQ + c*CK + t];
  float a2 = dtl * (-__expf(alog[h])) * LOG2E;
  s_dt[t] = dtl;
  s_acs2[t] = a2;
  __syncthreads();
  #pragma unroll
  for (int off=1; off<256; off<<=1){
    float v = (t>=off) ? s_acs2[t-off] : 0.f;
    __syncthreads();
    s_acs2[t] += v;
    __syncthreads();
  }
  float a2last = s_acs2[CK-1];
  s_w[t] = exp2f(a2last - s_acs2[t]);
  acsg2[((size_t)(b*NCH + c)*NH + h)*CK + t] = s_acs2[t];
  // stage xsT (dt-scaled x, transposed, swizzled)
  {
    const unsigned short* xp = xconv + (size_t)(b*LSEQ + c*CK)*CONVD + h*HD;
    int p = t & 63;
    int lw = t >> 6;
    #pragma unroll 8
    for (int k=0;k<64;k++){
      int l = 4*k + lw;
      float x = bf2f(xp[(size_t)l*CONVD + p]);
      s_xsT[p][l ^ ((p&7)<<3)] = f2bf(x * s_dt[l]);
    }
  }
  __syncthreads();

  // ---- phase 1 (MFMA): states[p][n] = sum_l (xs[l,p]*w[l]) * B[l,n] ----
  {
    ffrag acc[4][2];
    #pragma unroll
    for (int ps=0;ps<4;ps++)
      #pragma unroll
      for (int ns=0;ns<2;ns++){ acc[ps][ns][0]=0.f; acc[ps][ns][1]=0.f; acc[ps][ns][2]=0.f; acc[ps][ns][3]=0.f; }
    const unsigned short* btp = btg + (size_t)b*DSTATE*LSEQ + c*CK;
    #pragma unroll 2
    for (int ks=0; ks<8; ++ks){
      int lb = 32*ks + 8*g;
      float4 w0 = *(const float4*)&s_w[lb];
      float4 w1 = *(const float4*)&s_w[lb+4];
      bfrag bfr[2];
      #pragma unroll
      for (int ns=0; ns<2; ++ns){
        int n = 32*wv + 16*ns + cq;
        bfr[ns] = *(const bfrag*)(btp + (size_t)n*LSEQ + lb);
      }
      bfrag afr[4];
      #pragma unroll
      for (int ps=0; ps<4; ++ps){
        int p = 16*ps + cq;
        bfrag xv = *(const bfrag*)&s_xsT[p][lb ^ ((p&7)<<3)];
        float f[8];
        f[0]=bf2f((unsigned short)xv[0])*w0.x; f[1]=bf2f((unsigned short)xv[1])*w0.y;
        f[2]=bf2f((unsigned short)xv[2])*w0.z; f[3]=bf2f((unsigned short)xv[3])*w0.w;
        f[4]=bf2f((unsigned short)xv[4])*w1.x; f[5]=bf2f((unsigned short)xv[5])*w1.y;
        f[6]=bf2f((unsigned short)xv[6])*w1.z; f[7]=bf2f((unsigned short)xv[7])*w1.w;
        afr[ps] = pack8(f);
      }
      #pragma unroll
      for (int ps=0; ps<4; ++ps)
        #pragma unroll
        for (int ns=0; ns<2; ++ns)
          acc[ps][ns] = __builtin_amdgcn_mfma_f32_16x16x32_bf16(afr[ps], bfr[ns], acc[ps][ns], 0,0,0);
    }
    size_t sbase = ((size_t)((b*NCH + c)*NH + h))*HD*DSTATE;
    #pragma unroll
    for (int ps=0; ps<4; ++ps)
      #pragma unroll
      for (int ns=0; ns<2; ++ns)
        #pragma unroll
        for (int j=0; j<4; ++j){
          int p = 16*ps + 4*g + j, n = 32*wv + 16*ns + cq;
          states[sbase + (size_t)p*DSTATE + n] = f2bf(acc[ps][ns][j]);
        }
  }

  // ---- phase 2 (MFMA): Y_diag[l][p] = sum_{s<=l} G[l,s]*exp2(acs2_l-acs2_s)*xs[s][p] ----
  {
    ffrag acc[4][4];
    #pragma unroll
    for (int ls=0;ls<4;ls++)
      #pragma unroll
      for (int ps=0;ps<4;ps++){ acc[ls][ps][0]=0.f; acc[ls][ps][1]=0.f; acc[ls][ps][2]=0.f; acc[ls][ps][3]=0.f; }
    float a2l[4];
    #pragma unroll
    for (int ls=0; ls<4; ++ls) a2l[ls] = s_acs2[64*wv + 16*ls + cq];
    const unsigned short* gp = G + (size_t)(b*NCH + c)*CK*CK;
    int nks = 2*wv + 2;
    for (int ks=0; ks<nks; ++ks){
      int sb = 32*ks + 8*g;
      float4 e0 = *(const float4*)&s_acs2[sb];
      float4 e1 = *(const float4*)&s_acs2[sb+4];
      float a2s[8] = {e0.x,e0.y,e0.z,e0.w,e1.x,e1.y,e1.z,e1.w};
      bfrag bfr[4];
      #pragma unroll
      for (int ps=0; ps<4; ++ps){
        int p = 16*ps + cq;
        bfr[ps] = *(const bfrag*)&s_xsT[p][sb ^ ((p&7)<<3)];
      }
      bfrag afr[4];
      #pragma unroll
      for (int ls=0; ls<4; ++ls){
        int l = 64*wv + 16*ls + cq;
        bfrag gv = *(const bfrag*)(gp + (size_t)l*CK + sb);
        float f[8];
        #pragma unroll
        for (int i=0;i<8;i++){
          int s = sb + i;
          float cf = exp2f(a2l[ls] - a2s[i]);
          cf = (s <= l) ? cf : 0.f;
          f[i] = bf2f((unsigned short)gv[i]) * cf;
        }
        afr[ls] = pack8(f);
      }
      #pragma unroll
      for (int ls=0; ls<4; ++ls)
        #pragma unroll
        for (int ps=0; ps<4; ++ps)
          acc[ls][ps] = __builtin_amdgcn_mfma_f32_16x16x32_bf16(afr[ls], bfr[ps], acc[ls][ps], 0,0,0);
    }
    float* orow = out + (size_t)(b*LSEQ + c*CK)*DINNER + h*HD;
    #pragma unroll
    for (int ls=0; ls<4; ++ls)
      #pragma unroll
      for (int ps=0; ps<4; ++ps)
        #pragma unroll
        for (int j=0; j<4; ++j){
          int l = 64*wv + 16*ls + 4*g + j, p = 16*ps + cq;
          orow[(size_t)l*DINNER + p] = acc[ls][ps][j];
        }
  }
}

// ---------------- K3: inter-chunk state scan (in-place states -> prev_states) ----------------
__global__ __launch_bounds__(256) void k_scan(unsigned short* __restrict__ states,
    const float* __restrict__ acsg2)
{
  int bid = blockIdx.x;                     // NB*NH
  int h = bid & 31, b = bid >> 5;
  int t = threadIdx.x;
  float carry[32];
  #pragma unroll
  for (int r=0;r<32;r++) carry[r]=0.f;
  for (int c=0;c<NCH;c++){
    float cs = acsg2[((size_t)(b*NCH + c)*NH + h)*CK + (CK-1)];
    float dec = exp2f(cs);
    size_t base = ((size_t)((b*NCH + c)*NH + h))*HD*DSTATE;
    #pragma unroll
    for (int r=0;r<32;r++){
      size_t idx = base + t + 256*r;
      float cur = bf2f(states[idx]);
      states[idx] = f2bf(carry[r]);
      carry[r] = dec*carry[r] + cur;
    }
  }
}

// ---------------- K4 (MFMA): Y_off += exp2(acs2_l) * C_l . prev_state ----------------
__global__ __launch_bounds__(256) void k_yoff(const unsigned short* __restrict__ xconv,
  const unsigned short* __restrict__ states, const float* __restrict__ acsg2,
  float* __restrict__ out)
{
  int bid = blockIdx.x;                     // NB*NCH*NH
  int h = bid & 31, c = (bid>>5)&15, b = bid>>9;
  int t = threadIdx.x, lane = t & 63, wv = t >> 6;
  int cq = lane & 15, g = lane >> 4;
  const float* ac = acsg2 + ((size_t)(b*NCH + c)*NH + h)*CK;
  const unsigned short* crow = xconv + (size_t)(b*LSEQ + c*CK)*CONVD + DINNER + DSTATE;
  const unsigned short* psb = states + ((size_t)((b*NCH + c)*NH + h))*HD*DSTATE;
  ffrag acc[4][4];
  #pragma unroll
  for (int ls=0;ls<4;ls++)
    #pragma unroll
    for (int pp=0;pp<4;pp++){ acc[ls][pp][0]=0.f; acc[ls][pp][1]=0.f; acc[ls][pp][2]=0.f; acc[ls][pp][3]=0.f; }
  #pragma unroll
  for (int ks=0; ks<4; ++ks){
    int nb = 32*ks + 8*g;
    bfrag bfr[4];
    #pragma unroll
    for (int pp=0; pp<4; ++pp)
      bfr[pp] = *(const bfrag*)(psb + (size_t)(16*pp + cq)*DSTATE + nb);
    bfrag afr[4];
    #pragma unroll
    for (int ls=0; ls<4; ++ls){
      int l = 64*wv + 16*ls + cq;
      afr[ls] = *(const bfrag*)(crow + (size_t)l*CONVD + nb);
    }
    #pragma unroll
    for (int ls=0; ls<4; ++ls)
      #pragma unroll
      for (int pp=0; pp<4; ++pp)
        acc[ls][pp] = __builtin_amdgcn_mfma_f32_16x16x32_bf16(afr[ls], bfr[pp], acc[ls][pp], 0,0,0);
  }
  // apply el (f32) at store for precision
  float el[4][4];
  #pragma unroll
  for (int ls=0; ls<4; ++ls)
    #pragma unroll
    for (int j=0; j<4; ++j)
      el[ls][j] = exp2f(ac[64*wv + 16*ls + 4*g + j]);
  float* orow = out + (size_t)(b*LSEQ + c*CK)*DINNER + h*HD;
  #pragma unroll
  for (int ls=0; ls<4; ++ls)
    #pragma unroll
    for (int pp=0; pp<4; ++pp)
      #pragma unroll
      for (int j=0; j<4; ++j){
        int l = 64*wv + 16*ls + 4*g + j, p = 16*pp + cq;
        float* o = &orow[(size_t)l*DINNER + p];
        *o += el[ls][j] * acc[ls][pp][j];
      }
}

// ---------------- K5: + D*x, silu(z) gate, RMSNorm ----------------
__global__ __launch_bounds__(256) void k_final(const float* __restrict__ zx,
  const unsigned short* __restrict__ xconv, const float* __restrict__ dpar,
  const float* __restrict__ nw, float* __restrict__ out)
{
  int row = blockIdx.x;                     // b*LSEQ + l
  int t = threadIdx.x;
  float* orow = out + (size_t)row*DINNER;
  const float* zrow = zx + (size_t)row*DIN;
  const unsigned short* xrow = xconv + (size_t)row*CONVD;
  float vals[8];
  float ss = 0.f;
  #pragma unroll
  for (int k=0;k<2;k++){
    int i4 = t + 256*k;
    float4 y4 = *(const float4*)&orow[4*i4];
    float yv[4] = {y4.x, y4.y, y4.z, y4.w};
    #pragma unroll
    for (int e=0;e<4;e++){
      int d = 4*i4 + e;
      int hh = d >> 6;
      float x = bf2f(xrow[d]);
      float y = yv[e] + x*dpar[hh];
      float z = zrow[d];
      y *= z / (1.f + __expf(-z));
      vals[4*k+e] = y;
      ss += y*y;
    }
  }
  #pragma unroll
  for (int off=1; off<64; off<<=1) ss += __shfl_xor(ss, off, 64);
  __shared__ float red[4];
  if ((t & 63) == 0) red[t>>6] = ss;
  __syncthreads();
  float tot = red[0]+red[1]+red[2]+red[3];
  float rms = rsqrtf(tot * (1.f/(float)DINNER) + 1e-5f);
  #pragma unroll
  for (int k=0;k<2;k++){
    int i4 = t + 256*k;
    float4 w4 = *(const float4*)&nw[4*i4];
    float4 o;
    o.x = vals[4*k+0]*rms*w4.x;
    o.y = vals[4*k+1]*rms*w4.y;
    o.z = vals[4*k+2]*rms*w4.z;
    o.w = vals[4*k+3]*rms*w4.w;
    *(float4*)&orow[4*i4] = o;
  }
}

extern "C" void kernel_launch(void* const* d_in, const int* in_sizes, int n_in,
                              void* d_out, int out_size, void* d_ws, size_t ws_size,
                              hipStream_t stream)
{
  const float* zx   = (const float*)d_in[0];
  const float* cw   = (const float*)d_in[1];
  const float* cb   = (const float*)d_in[2];
  const float* dtb  = (const float*)d_in[3];
  const float* alog = (const float*)d_in[4];
  const float* dpar = (const float*)d_in[5];
  const float* nw   = (const float*)d_in[6];
  float* out = (float*)d_out;
  char* ws = (char*)d_ws;

  // ws layout (bytes):
  unsigned short* xconv  = (unsigned short*)(ws);             // 37,748,736
  unsigned short* btg    = (unsigned short*)(ws + 37748736);  //  2,097,152
  float*          dtv    = (float*)(ws + 39845888);           //  1,048,576
  float*          acsg2  = (float*)(ws + 40894464);           //  1,048,576
  unsigned short* states = (unsigned short*)(ws + 41943040);  // 16,777,216
  unsigned short* G      = (unsigned short*)(ws + 58720256);  //  4,194,304
  // total 62,914,560 bytes

  hipLaunchKernelGGL(k_conv,  dim3(73728), dim3(256), 0, stream, zx, cw, cb, xconv);
  hipLaunchKernelGGL(k_dt,    dim3(1024),  dim3(256), 0, stream, zx, dtb, dtv);
  hipLaunchKernelGGL(k_tr,    dim3(NB*64), dim3(256), 0, stream, xconv, btg);
  hipLaunchKernelGGL(k_gmat,  dim3(NB*NCH*16), dim3(256), 0, stream, xconv, G);
  hipLaunchKernelGGL(k_chunk, dim3(NB*NCH*NH), dim3(256), 0, stream, xconv, btg, dtv, alog, G, states, acsg2, out);
  hipLaunchKernelGGL(k_scan,  dim3(NB*NH),  dim3(256), 0, stream, states, acsg2);
  hipLaunchKernelGGL(k_yoff,  dim3(NB*NCH*NH), dim3(256), 0, stream, xconv, states, acsg2, out);
  hipLaunchKernelGGL(k_final, dim3(NB*LSEQ), dim3(256), 0, stream, zx, xconv, dpar, nw, out);
}

// Round 3
// 383.028 us; speedup vs baseline: 1.9637x; 1.2113x over previous
//
#include <hip/hip_runtime.h>
#include <hip/hip_bf16.h>

#define NB 2
#define LSEQ 4096
#define DIN 4384
#define DINNER 2048
#define DSTATE 128
#define CONVD 2304
#define HD 64
#define NH 32
#define CK 256
#define NCH 16

typedef __attribute__((ext_vector_type(8))) short bfrag;
typedef __attribute__((ext_vector_type(4))) float ffrag;

__device__ __forceinline__ float bf2f(unsigned short u){ return __uint_as_float(((unsigned int)u)<<16); }
__device__ __forceinline__ unsigned short f2bf(float f){
  unsigned int u = __float_as_uint(f);
  unsigned int r = (u + 0x7fffu + ((u>>16)&1u)) >> 16;
  return (unsigned short)r;
}
__device__ __forceinline__ unsigned int pk2(float a, float b){
  return (unsigned)f2bf(a) | ((unsigned)f2bf(b) << 16);
}
__device__ __forceinline__ float blo(unsigned int u){ return __uint_as_float(u<<16); }
__device__ __forceinline__ float bhi(unsigned int u){ return __uint_as_float(u & 0xffff0000u); }
__device__ __forceinline__ bfrag pack8(const float* f){
  bfrag r;
  #pragma unroll
  for (int i=0;i<8;i++) r[i] = (short)f2bf(f[i]);
  return r;
}

// ---------------- K1: causal conv + silu -> xconv (bf16), tiled sliding-window ----------------
__global__ __launch_bounds__(256) void k_conv(const float* __restrict__ zx,
    const float* __restrict__ cw, const float* __restrict__ cb,
    unsigned short* __restrict__ xconv)
{
  int bid = blockIdx.x;                     // NB * 64 * 9
  int ct = bid % 9;
  int rt = bid / 9;
  int b = rt >> 6, lt = rt & 63;
  int t = threadIdx.x;
  int q = t & 63, lg = t >> 6;
  int c0 = ct*256 + q*4;
  const float* colp = zx + (size_t)b*LSEQ*DIN + DINNER + c0;
  float4 w0 = *(const float4*)&cw[(c0+0)*4];
  float4 w1 = *(const float4*)&cw[(c0+1)*4];
  float4 w2 = *(const float4*)&cw[(c0+2)*4];
  float4 w3 = *(const float4*)&cw[(c0+3)*4];
  float4 bias = *(const float4*)&cb[c0];
  int l0 = lt*64 + lg*16;
  float4 win0, win1, win2, win3;
  win0 = (l0-3 >= 0) ? *(const float4*)(colp + (size_t)(l0-3)*DIN) : make_float4(0,0,0,0);
  win1 = (l0-2 >= 0) ? *(const float4*)(colp + (size_t)(l0-2)*DIN) : make_float4(0,0,0,0);
  win2 = (l0-1 >= 0) ? *(const float4*)(colp + (size_t)(l0-1)*DIN) : make_float4(0,0,0,0);
  unsigned short* op = xconv + (size_t)(b*LSEQ)*CONVD + c0;
  #pragma unroll 4
  for (int i=0;i<16;i++){
    int l = l0 + i;
    win3 = *(const float4*)(colp + (size_t)l*DIN);
    float o0 = bias.x + w0.x*win0.x + w0.y*win1.x + w0.z*win2.x + w0.w*win3.x;
    float o1 = bias.y + w1.x*win0.y + w1.y*win1.y + w1.z*win2.y + w1.w*win3.y;
    float o2 = bias.z + w2.x*win0.z + w2.y*win1.z + w2.z*win2.z + w2.w*win3.z;
    float o3 = bias.w + w3.x*win0.w + w3.y*win1.w + w3.z*win2.w + w3.w*win3.w;
    o0 = o0 / (1.f + __expf(-o0));
    o1 = o1 / (1.f + __expf(-o1));
    o2 = o2 / (1.f + __expf(-o2));
    o3 = o3 / (1.f + __expf(-o3));
    uint2 pk; pk.x = pk2(o0,o1); pk.y = pk2(o2,o3);
    *(uint2*)&op[(size_t)l*CONVD] = pk;
    win0 = win1; win1 = win2; win2 = win3;
  }
}

// ---------------- K1b: dt = clip(softplus(raw+bias),0,100), layout [b][h][L] ----------------
__global__ __launch_bounds__(256) void k_dt(const float* __restrict__ zx,
    const float* __restrict__ dtb, float* __restrict__ dtv)
{
  int idx = blockIdx.x*256 + threadIdx.x;   // NB*NH*LSEQ
  int l = idx & (LSEQ-1);
  int bh = idx >> 12;
  int h = bh & 31, b = bh >> 5;
  float x = zx[(size_t)(b*LSEQ + l)*DIN + DINNER + CONVD + h] + dtb[h];
  float sp = (x > 20.f) ? x : log1pf(__expf(x));
  dtv[idx] = fminf(sp, 100.f);
}

// ---------------- K1c: transpose B slice -> BtG[b][n][L] (bf16) ----------------
__global__ __launch_bounds__(256) void k_tr(const unsigned short* __restrict__ xconv,
    unsigned short* __restrict__ btg)
{
  __shared__ unsigned short sT[128][72];
  int bid = blockIdx.x;                     // b*64 + tile
  int b = bid >> 6, tile = bid & 63;
  int l0 = tile * 64;
  int t = threadIdx.x;
  #pragma unroll
  for (int k=0;k<32;k++){
    int idx = 256*k + t;
    int l = idx >> 7, n = idx & 127;
    sT[n][l] = xconv[(size_t)(b*LSEQ + l0 + l)*CONVD + DINNER + n];
  }
  __syncthreads();
  #pragma unroll
  for (int k=0;k<32;k++){
    int idx = 256*k + t;
    int n = idx >> 6, l = idx & 63;
    btg[(size_t)(b*DSTATE + n)*LSEQ + l0 + l] = sT[n][l];
  }
}

// ---------------- K2a (MFMA): G[l][s] = sum_n C[l,n]*B[s,n], bf16 l-major ----------------
__global__ __launch_bounds__(256) void k_gmat(const unsigned short* __restrict__ xconv,
    unsigned short* __restrict__ G)
{
  int bid = blockIdx.x;                     // NB*NCH*16
  int st = bid & 3, lt = (bid>>2)&3, c = (bid>>4)&15, b = bid>>8;
  if (st > lt) return;                      // only lower-tri tiles needed
  int t = threadIdx.x, lane = t & 63, wv = t >> 6;
  int cq = lane & 15, g = lane >> 4;
  const unsigned short* base = xconv + (size_t)(b*LSEQ + c*CK)*CONVD;
  ffrag acc[4];
  #pragma unroll
  for (int ss=0; ss<4; ++ss){ acc[ss][0]=0.f; acc[ss][1]=0.f; acc[ss][2]=0.f; acc[ss][3]=0.f; }
  #pragma unroll
  for (int ks=0; ks<4; ++ks){
    int nb = 32*ks + 8*g;
    int l = lt*64 + 16*wv + cq;
    bfrag afr = *(const bfrag*)(base + (size_t)l*CONVD + DINNER + DSTATE + nb);
    #pragma unroll
    for (int ss=0; ss<4; ++ss){
      int s = st*64 + 16*ss + cq;
      bfrag bfr = *(const bfrag*)(base + (size_t)s*CONVD + DINNER + nb);
      acc[ss] = __builtin_amdgcn_mfma_f32_16x16x32_bf16(afr, bfr, acc[ss], 0,0,0);
    }
  }
  unsigned short* gp = G + (size_t)(b*NCH + c)*CK*CK;
  #pragma unroll
  for (int ss=0; ss<4; ++ss)
    #pragma unroll
    for (int j=0; j<4; ++j){
      int l = lt*64 + 16*wv + 4*g + j, s = st*64 + 16*ss + cq;
      gp[(size_t)l*CK + s] = f2bf(acc[ss][j]);
    }
}

// ---------------- K2b: acs + states(MFMA) + Y_diag(MFMA), per (b,chunk,h) ----------------
__global__ __launch_bounds__(256) void k_chunk(const unsigned short* __restrict__ xconv,
   const unsigned short* __restrict__ btg,
   const float* __restrict__ dtv, const float* __restrict__ alog,
   const unsigned short* __restrict__ G,
   unsigned short* __restrict__ states,
   float* __restrict__ acsg2, float* __restrict__ out)
{
  int bid = blockIdx.x;                     // NB*NCH*NH
  int h = bid & 31, c = (bid>>5)&15, b = bid>>9;
  int t = threadIdx.x, lane = t & 63, wv = t >> 6;
  int cq = lane & 15, g = lane >> 4;
  __shared__ float s_acs2[CK];
  __shared__ float s_w[CK];
  __shared__ float s_dt[CK];
  __shared__ unsigned short s_xsT[64][256];  // [p][l], l XOR-swizzled by ((p&7)<<3)

  const float LOG2E = 1.44269504088896340736f;
  float dtl = dtv[(size_t)(b*NH + h)*LSEQ + c*CK + t];
  float a2 = dtl * (-__expf(alog[h])) * LOG2E;
  s_dt[t] = dtl;
  s_acs2[t] = a2;
  __syncthreads();
  #pragma unroll
  for (int off=1; off<256; off<<=1){
    float v = (t>=off) ? s_acs2[t-off] : 0.f;
    __syncthreads();
    s_acs2[t] += v;
    __syncthreads();
  }
  float a2last = s_acs2[CK-1];
  s_w[t] = exp2f(a2last - s_acs2[t]);
  acsg2[((size_t)(b*NCH + c)*NH + h)*CK + t] = s_acs2[t];
  // stage xsT (dt-scaled x, transposed, swizzled)
  {
    const unsigned short* xp = xconv + (size_t)(b*LSEQ + c*CK)*CONVD + h*HD;
    int p = t & 63;
    int lw = t >> 6;
    #pragma unroll 8
    for (int k=0;k<64;k++){
      int l = 4*k + lw;
      float x = bf2f(xp[(size_t)l*CONVD + p]);
      s_xsT[p][l ^ ((p&7)<<3)] = f2bf(x * s_dt[l]);
    }
  }
  __syncthreads();

  // ---- phase 1 (MFMA): states[p][n] = sum_l (xs[l,p]*w[l]) * B[l,n] ----
  {
    ffrag acc[4][2];
    #pragma unroll
    for (int ps=0;ps<4;ps++)
      #pragma unroll
      for (int ns=0;ns<2;ns++){ acc[ps][ns][0]=0.f; acc[ps][ns][1]=0.f; acc[ps][ns][2]=0.f; acc[ps][ns][3]=0.f; }
    const unsigned short* btp = btg + (size_t)b*DSTATE*LSEQ + c*CK;
    #pragma unroll 2
    for (int ks=0; ks<8; ++ks){
      int lb = 32*ks + 8*g;
      float4 w0 = *(const float4*)&s_w[lb];
      float4 w1 = *(const float4*)&s_w[lb+4];
      bfrag bfr[2];
      #pragma unroll
      for (int ns=0; ns<2; ++ns){
        int n = 32*wv + 16*ns + cq;
        bfr[ns] = *(const bfrag*)(btp + (size_t)n*LSEQ + lb);
      }
      bfrag afr[4];
      #pragma unroll
      for (int ps=0; ps<4; ++ps){
        int p = 16*ps + cq;
        bfrag xv = *(const bfrag*)&s_xsT[p][lb ^ ((p&7)<<3)];
        float f[8];
        f[0]=bf2f((unsigned short)xv[0])*w0.x; f[1]=bf2f((unsigned short)xv[1])*w0.y;
        f[2]=bf2f((unsigned short)xv[2])*w0.z; f[3]=bf2f((unsigned short)xv[3])*w0.w;
        f[4]=bf2f((unsigned short)xv[4])*w1.x; f[5]=bf2f((unsigned short)xv[5])*w1.y;
        f[6]=bf2f((unsigned short)xv[6])*w1.z; f[7]=bf2f((unsigned short)xv[7])*w1.w;
        afr[ps] = pack8(f);
      }
      #pragma unroll
      for (int ps=0; ps<4; ++ps)
        #pragma unroll
        for (int ns=0; ns<2; ++ns)
          acc[ps][ns] = __builtin_amdgcn_mfma_f32_16x16x32_bf16(afr[ps], bfr[ns], acc[ps][ns], 0,0,0);
    }
    size_t sbase = ((size_t)((b*NCH + c)*NH + h))*HD*DSTATE;
    #pragma unroll
    for (int ps=0; ps<4; ++ps)
      #pragma unroll
      for (int ns=0; ns<2; ++ns)
        #pragma unroll
        for (int j=0; j<4; ++j){
          int p = 16*ps + 4*g + j, n = 32*wv + 16*ns + cq;
          states[sbase + (size_t)p*DSTATE + n] = f2bf(acc[ps][ns][j]);
        }
  }

  // ---- phase 2 (MFMA): Y_diag[l][p] = sum_{s<=l} G[l,s]*exp2(acs2_l-acs2_s)*xs[s][p] ----
  {
    ffrag acc[4][4];
    #pragma unroll
    for (int ls=0;ls<4;ls++)
      #pragma unroll
      for (int ps=0;ps<4;ps++){ acc[ls][ps][0]=0.f; acc[ls][ps][1]=0.f; acc[ls][ps][2]=0.f; acc[ls][ps][3]=0.f; }
    float a2l[4];
    #pragma unroll
    for (int ls=0; ls<4; ++ls) a2l[ls] = s_acs2[64*wv + 16*ls + cq];
    const unsigned short* gp = G + (size_t)(b*NCH + c)*CK*CK;
    int nks = 2*wv + 2;
    for (int ks=0; ks<nks; ++ks){
      int sb = 32*ks + 8*g;
      float4 e0 = *(const float4*)&s_acs2[sb];
      float4 e1 = *(const float4*)&s_acs2[sb+4];
      float a2s[8] = {e0.x,e0.y,e0.z,e0.w,e1.x,e1.y,e1.z,e1.w};
      bfrag bfr[4];
      #pragma unroll
      for (int ps=0; ps<4; ++ps){
        int p = 16*ps + cq;
        bfr[ps] = *(const bfrag*)&s_xsT[p][sb ^ ((p&7)<<3)];
      }
      bfrag afr[4];
      #pragma unroll
      for (int ls=0; ls<4; ++ls){
        int l = 64*wv + 16*ls + cq;
        bfrag gv = *(const bfrag*)(gp + (size_t)l*CK + sb);
        float f[8];
        #pragma unroll
        for (int i=0;i<8;i++){
          int s = sb + i;
          float cf = exp2f(a2l[ls] - a2s[i]);
          cf = (s <= l) ? cf : 0.f;
          f[i] = bf2f((unsigned short)gv[i]) * cf;
        }
        afr[ls] = pack8(f);
      }
      #pragma unroll
      for (int ls=0; ls<4; ++ls)
        #pragma unroll
        for (int ps=0; ps<4; ++ps)
          acc[ls][ps] = __builtin_amdgcn_mfma_f32_16x16x32_bf16(afr[ls], bfr[ps], acc[ls][ps], 0,0,0);
    }
    float* orow = out + (size_t)(b*LSEQ + c*CK)*DINNER + h*HD;
    #pragma unroll
    for (int ls=0; ls<4; ++ls)
      #pragma unroll
      for (int ps=0; ps<4; ++ps)
        #pragma unroll
        for (int j=0; j<4; ++j){
          int l = 64*wv + 16*ls + 4*g + j, p = 16*ps + cq;
          orow[(size_t)l*DINNER + p] = acc[ls][ps][j];
        }
  }
}

// ---------------- K3: inter-chunk state scan (in-place, split 8-way for occupancy) ----------------
__global__ __launch_bounds__(256) void k_scan(unsigned short* __restrict__ states,
    const float* __restrict__ acsg2)
{
  int bid = blockIdx.x;                     // NB*NH*8
  int sub = bid & 7, h = (bid>>3) & 31, b = bid >> 8;
  int t = threadIdx.x;
  int e0 = sub*1024 + t*4;
  float c0=0.f, c1=0.f, c2=0.f, c3=0.f;
  for (int c=0;c<NCH;c++){
    float dec = exp2f(acsg2[((size_t)(b*NCH + c)*NH + h)*CK + (CK-1)]);
    size_t base = ((size_t)((b*NCH + c)*NH + h))*HD*DSTATE + e0;
    uint2 v = *(uint2*)&states[base];
    float u0 = blo(v.x), u1 = bhi(v.x), u2 = blo(v.y), u3 = bhi(v.y);
    uint2 w; w.x = pk2(c0,c1); w.y = pk2(c2,c3);
    *(uint2*)&states[base] = w;
    c0 = dec*c0 + u0; c1 = dec*c1 + u1; c2 = dec*c2 + u2; c3 = dec*c3 + u3;
  }
}

// ---------------- K4 (MFMA): Y_off += exp2(acs2_l) * C_l . prev_state ----------------
__global__ __launch_bounds__(256) void k_yoff(const unsigned short* __restrict__ xconv,
  const unsigned short* __restrict__ states, const float* __restrict__ acsg2,
  float* __restrict__ out)
{
  int bid = blockIdx.x;                     // NB*NCH*NH
  int h = bid & 31, c = (bid>>5)&15, b = bid>>9;
  int t = threadIdx.x, lane = t & 63, wv = t >> 6;
  int cq = lane & 15, g = lane >> 4;
  const float* ac = acsg2 + ((size_t)(b*NCH + c)*NH + h)*CK;
  const unsigned short* crow = xconv + (size_t)(b*LSEQ + c*CK)*CONVD + DINNER + DSTATE;
  const unsigned short* psb = states + ((size_t)((b*NCH + c)*NH + h))*HD*DSTATE;
  ffrag acc[4][4];
  #pragma unroll
  for (int ls=0;ls<4;ls++)
    #pragma unroll
    for (int pp=0;pp<4;pp++){ acc[ls][pp][0]=0.f; acc[ls][pp][1]=0.f; acc[ls][pp][2]=0.f; acc[ls][pp][3]=0.f; }
  #pragma unroll
  for (int ks=0; ks<4; ++ks){
    int nb = 32*ks + 8*g;
    bfrag bfr[4];
    #pragma unroll
    for (int pp=0; pp<4; ++pp)
      bfr[pp] = *(const bfrag*)(psb + (size_t)(16*pp + cq)*DSTATE + nb);
    bfrag afr[4];
    #pragma unroll
    for (int ls=0; ls<4; ++ls){
      int l = 64*wv + 16*ls + cq;
      afr[ls] = *(const bfrag*)(crow + (size_t)l*CONVD + nb);
    }
    #pragma unroll
    for (int ls=0; ls<4; ++ls)
      #pragma unroll
      for (int pp=0; pp<4; ++pp)
        acc[ls][pp] = __builtin_amdgcn_mfma_f32_16x16x32_bf16(afr[ls], bfr[pp], acc[ls][pp], 0,0,0);
  }
  float el[4][4];
  #pragma unroll
  for (int ls=0; ls<4; ++ls)
    #pragma unroll
    for (int j=0; j<4; ++j)
      el[ls][j] = exp2f(ac[64*wv + 16*ls + 4*g + j]);
  float* orow = out + (size_t)(b*LSEQ + c*CK)*DINNER + h*HD;
  #pragma unroll
  for (int ls=0; ls<4; ++ls)
    #pragma unroll
    for (int pp=0; pp<4; ++pp)
      #pragma unroll
      for (int j=0; j<4; ++j){
        int l = 64*wv + 16*ls + 4*g + j, p = 16*pp + cq;
        float* o = &orow[(size_t)l*DINNER + p];
        *o += el[ls][j] * acc[ls][pp][j];
      }
}

// ---------------- K5: + D*x, silu(z) gate, RMSNorm ----------------
__global__ __launch_bounds__(256) void k_final(const float* __restrict__ zx,
  const unsigned short* __restrict__ xconv, const float* __restrict__ dpar,
  const float* __restrict__ nw, float* __restrict__ out)
{
  int row = blockIdx.x;                     // b*LSEQ + l
  int t = threadIdx.x;
  float* orow = out + (size_t)row*DINNER;
  const float* zrow = zx + (size_t)row*DIN;
  const unsigned short* xrow = xconv + (size_t)row*CONVD;
  float vals[8];
  float ss = 0.f;
  #pragma unroll
  for (int k=0;k<2;k++){
    int i4 = t + 256*k;
    float4 y4 = *(const float4*)&orow[4*i4];
    float yv[4] = {y4.x, y4.y, y4.z, y4.w};
    #pragma unroll
    for (int e=0;e<4;e++){
      int d = 4*i4 + e;
      int hh = d >> 6;
      float x = bf2f(xrow[d]);
      float y = yv[e] + x*dpar[hh];
      float z = zrow[d];
      y *= z / (1.f + __expf(-z));
      vals[4*k+e] = y;
      ss += y*y;
    }
  }
  #pragma unroll
  for (int off=1; off<64; off<<=1) ss += __shfl_xor(ss, off, 64);
  __shared__ float red[4];
  if ((t & 63) == 0) red[t>>6] = ss;
  __syncthreads();
  float tot = red[0]+red[1]+red[2]+red[3];
  float rms = rsqrtf(tot * (1.f/(float)DINNER) + 1e-5f);
  #pragma unroll
  for (int k=0;k<2;k++){
    int i4 = t + 256*k;
    float4 w4 = *(const float4*)&nw[4*i4];
    float4 o;
    o.x = vals[4*k+0]*rms*w4.x;
    o.y = vals[4*k+1]*rms*w4.y;
    o.z = vals[4*k+2]*rms*w4.z;
    o.w = vals[4*k+3]*rms*w4.w;
    *(float4*)&orow[4*i4] = o;
  }
}

extern "C" void kernel_launch(void* const* d_in, const int* in_sizes, int n_in,
                              void* d_out, int out_size, void* d_ws, size_t ws_size,
                              hipStream_t stream)
{
  const float* zx   = (const float*)d_in[0];
  const float* cw   = (const float*)d_in[1];
  const float* cb   = (const float*)d_in[2];
  const float* dtb  = (const float*)d_in[3];
  const float* alog = (const float*)d_in[4];
  const float* dpar = (const float*)d_in[5];
  const float* nw   = (const float*)d_in[6];
  float* out = (float*)d_out;
  char* ws = (char*)d_ws;

  // ws layout (bytes):
  unsigned short* xconv  = (unsigned short*)(ws);             // 37,748,736
  unsigned short* btg    = (unsigned short*)(ws + 37748736);  //  2,097,152
  float*          dtv    = (float*)(ws + 39845888);           //  1,048,576
  float*          acsg2  = (float*)(ws + 40894464);           //  1,048,576
  unsigned short* states = (unsigned short*)(ws + 41943040);  // 16,777,216
  unsigned short* G      = (unsigned short*)(ws + 58720256);  //  4,194,304
  // total 62,914,560 bytes

  hipLaunchKernelGGL(k_conv,  dim3(NB*64*9), dim3(256), 0, stream, zx, cw, cb, xconv);
  hipLaunchKernelGGL(k_dt,    dim3(1024),  dim3(256), 0, stream, zx, dtb, dtv);
  hipLaunchKernelGGL(k_tr,    dim3(NB*64), dim3(256), 0, stream, xconv, btg);
  hipLaunchKernelGGL(k_gmat,  dim3(NB*NCH*16), dim3(256), 0, stream, xconv, G);
  hipLaunchKernelGGL(k_chunk, dim3(NB*NCH*NH), dim3(256), 0, stream, xconv, btg, dtv, alog, G, states, acsg2, out);
  hipLaunchKernelGGL(k_scan,  dim3(NB*NH*8),  dim3(256), 0, stream, states, acsg2);
  hipLaunchKernelGGL(k_yoff,  dim3(NB*NCH*NH), dim3(256), 0, stream, xconv, states, acsg2, out);
  hipLaunchKernelGGL(k_final, dim3(NB*LSEQ), dim3(256), 0, stream, zx, xconv, dpar, nw, out);
}

// Round 4
// 342.940 us; speedup vs baseline: 2.1933x; 1.1169x over previous
//
#include <hip/hip_runtime.h>
#include <hip/hip_bf16.h>

#define NB 2
#define LSEQ 4096
#define DIN 4384
#define DINNER 2048
#define DSTATE 128
#define CONVD 2304
#define HD 64
#define NH 32
#define CK 256
#define NCH 16

typedef __attribute__((ext_vector_type(8))) short bfrag;
typedef __attribute__((ext_vector_type(4))) float ffrag;

__device__ __forceinline__ float bf2f(unsigned short u){ return __uint_as_float(((unsigned int)u)<<16); }
__device__ __forceinline__ unsigned short f2bf(float f){
  unsigned int u = __float_as_uint(f);
  unsigned int r = (u + 0x7fffu + ((u>>16)&1u)) >> 16;
  return (unsigned short)r;
}
__device__ __forceinline__ unsigned int pk2(float a, float b){
  return (unsigned)f2bf(a) | ((unsigned)f2bf(b) << 16);
}
__device__ __forceinline__ float blo(unsigned int u){ return __uint_as_float(u<<16); }
__device__ __forceinline__ float bhi(unsigned int u){ return __uint_as_float(u & 0xffff0000u); }
__device__ __forceinline__ bfrag pack8(const float* f){
  bfrag r;
  #pragma unroll
  for (int i=0;i<8;i++) r[i] = (short)f2bf(f[i]);
  return r;
}

// ---------------- K1: causal conv + silu -> xconv (bf16), tiled sliding-window ----------------
__global__ __launch_bounds__(256) void k_conv(const float* __restrict__ zx,
    const float* __restrict__ cw, const float* __restrict__ cb,
    unsigned short* __restrict__ xconv)
{
  int bid = blockIdx.x;                     // NB * 64 * 9
  int ct = bid % 9;
  int rt = bid / 9;
  int b = rt >> 6, lt = rt & 63;
  int t = threadIdx.x;
  int q = t & 63, lg = t >> 6;
  int c0 = ct*256 + q*4;
  const float* colp = zx + (size_t)b*LSEQ*DIN + DINNER + c0;
  float4 w0 = *(const float4*)&cw[(c0+0)*4];
  float4 w1 = *(const float4*)&cw[(c0+1)*4];
  float4 w2 = *(const float4*)&cw[(c0+2)*4];
  float4 w3 = *(const float4*)&cw[(c0+3)*4];
  float4 bias = *(const float4*)&cb[c0];
  int l0 = lt*64 + lg*16;
  float4 win0, win1, win2, win3;
  win0 = (l0-3 >= 0) ? *(const float4*)(colp + (size_t)(l0-3)*DIN) : make_float4(0,0,0,0);
  win1 = (l0-2 >= 0) ? *(const float4*)(colp + (size_t)(l0-2)*DIN) : make_float4(0,0,0,0);
  win2 = (l0-1 >= 0) ? *(const float4*)(colp + (size_t)(l0-1)*DIN) : make_float4(0,0,0,0);
  unsigned short* op = xconv + (size_t)(b*LSEQ)*CONVD + c0;
  #pragma unroll 4
  for (int i=0;i<16;i++){
    int l = l0 + i;
    win3 = *(const float4*)(colp + (size_t)l*DIN);
    float o0 = bias.x + w0.x*win0.x + w0.y*win1.x + w0.z*win2.x + w0.w*win3.x;
    float o1 = bias.y + w1.x*win0.y + w1.y*win1.y + w1.z*win2.y + w1.w*win3.y;
    float o2 = bias.z + w2.x*win0.z + w2.y*win1.z + w2.z*win2.z + w2.w*win3.z;
    float o3 = bias.w + w3.x*win0.w + w3.y*win1.w + w3.z*win2.w + w3.w*win3.w;
    o0 = o0 / (1.f + __expf(-o0));
    o1 = o1 / (1.f + __expf(-o1));
    o2 = o2 / (1.f + __expf(-o2));
    o3 = o3 / (1.f + __expf(-o3));
    uint2 pk; pk.x = pk2(o0,o1); pk.y = pk2(o2,o3);
    *(uint2*)&op[(size_t)l*CONVD] = pk;
    win0 = win1; win1 = win2; win2 = win3;
  }
}

// ---------------- K1b: dt = clip(softplus(raw+bias),0,100), layout [b][h][L] ----------------
__global__ __launch_bounds__(256) void k_dt(const float* __restrict__ zx,
    const float* __restrict__ dtb, float* __restrict__ dtv)
{
  int idx = blockIdx.x*256 + threadIdx.x;   // NB*NH*LSEQ
  int l = idx & (LSEQ-1);
  int bh = idx >> 12;
  int h = bh & 31, b = bh >> 5;
  float x = zx[(size_t)(b*LSEQ + l)*DIN + DINNER + CONVD + h] + dtb[h];
  float sp = (x > 20.f) ? x : log1pf(__expf(x));
  dtv[idx] = fminf(sp, 100.f);
}

// ---------------- K1c: transpose B slice -> BtG[b][n][L] (bf16) ----------------
__global__ __launch_bounds__(256) void k_tr(const unsigned short* __restrict__ xconv,
    unsigned short* __restrict__ btg)
{
  __shared__ unsigned short sT[128][72];
  int bid = blockIdx.x;                     // b*64 + tile
  int b = bid >> 6, tile = bid & 63;
  int l0 = tile * 64;
  int t = threadIdx.x;
  #pragma unroll
  for (int k=0;k<32;k++){
    int idx = 256*k + t;
    int l = idx >> 7, n = idx & 127;
    sT[n][l] = xconv[(size_t)(b*LSEQ + l0 + l)*CONVD + DINNER + n];
  }
  __syncthreads();
  #pragma unroll
  for (int k=0;k<32;k++){
    int idx = 256*k + t;
    int n = idx >> 6, l = idx & 63;
    btg[(size_t)(b*DSTATE + n)*LSEQ + l0 + l] = sT[n][l];
  }
}

// ---------------- K2a (MFMA): G[l][s] = sum_n C[l,n]*B[s,n], bf16 l-major ----------------
__constant__ int g_lt[10] = {0,1,1,2,2,2,3,3,3,3};
__constant__ int g_st[10] = {0,0,1,0,1,2,0,1,2,3};
__global__ __launch_bounds__(256) void k_gmat(const unsigned short* __restrict__ xconv,
    unsigned short* __restrict__ G)
{
  int bid = blockIdx.x;                     // NB*NCH*10
  int pr = bid % 10;
  int cc = bid / 10;
  int c = cc & 15, b = cc >> 4;
  int lt = g_lt[pr], st = g_st[pr];
  int t = threadIdx.x, lane = t & 63, wv = t >> 6;
  int cq = lane & 15, g = lane >> 4;
  const unsigned short* base = xconv + (size_t)(b*LSEQ + c*CK)*CONVD;
  ffrag acc[4];
  #pragma unroll
  for (int ss=0; ss<4; ++ss){ acc[ss][0]=0.f; acc[ss][1]=0.f; acc[ss][2]=0.f; acc[ss][3]=0.f; }
  #pragma unroll
  for (int ks=0; ks<4; ++ks){
    int nb = 32*ks + 8*g;
    int l = lt*64 + 16*wv + cq;
    bfrag afr = *(const bfrag*)(base + (size_t)l*CONVD + DINNER + DSTATE + nb);
    #pragma unroll
    for (int ss=0; ss<4; ++ss){
      int s = st*64 + 16*ss + cq;
      bfrag bfr = *(const bfrag*)(base + (size_t)s*CONVD + DINNER + nb);
      acc[ss] = __builtin_amdgcn_mfma_f32_16x16x32_bf16(afr, bfr, acc[ss], 0,0,0);
    }
  }
  unsigned short* gp = G + (size_t)(b*NCH + c)*CK*CK;
  #pragma unroll
  for (int ss=0; ss<4; ++ss)
    #pragma unroll
    for (int j=0; j<4; ++j){
      int l = lt*64 + 16*wv + 4*g + j, s = st*64 + 16*ss + cq;
      gp[(size_t)l*CK + s] = f2bf(acc[ss][j]);
    }
}

// ---------------- K2b: acs scan + states(MFMA), per (b,chunk,h) ----------------
__global__ __launch_bounds__(256) void k_states(const unsigned short* __restrict__ xconv,
   const unsigned short* __restrict__ btg,
   const float* __restrict__ dtv, const float* __restrict__ alog,
   unsigned short* __restrict__ states,
   float* __restrict__ acsg2)
{
  int bid = blockIdx.x;                     // NB*NCH*NH
  int h = bid & 31, c = (bid>>5)&15, b = bid>>9;
  int t = threadIdx.x, lane = t & 63, wv = t >> 6;
  int cq = lane & 15, g = lane >> 4;
  __shared__ float s_acs2[CK];
  __shared__ float s_w[CK];
  __shared__ float s_dt[CK];
  __shared__ unsigned short s_xsT[64][256];  // [p][l], l XOR-swizzled by ((p&7)<<3)

  const float LOG2E = 1.44269504088896340736f;
  float dtl = dtv[(size_t)(b*NH + h)*LSEQ + c*CK + t];
  float a2 = dtl * (-__expf(alog[h])) * LOG2E;
  s_dt[t] = dtl;
  s_acs2[t] = a2;
  __syncthreads();
  #pragma unroll
  for (int off=1; off<256; off<<=1){
    float v = (t>=off) ? s_acs2[t-off] : 0.f;
    __syncthreads();
    s_acs2[t] += v;
    __syncthreads();
  }
  float a2last = s_acs2[CK-1];
  s_w[t] = exp2f(a2last - s_acs2[t]);
  acsg2[((size_t)(b*NCH + c)*NH + h)*CK + t] = s_acs2[t];
  {
    const unsigned short* xp = xconv + (size_t)(b*LSEQ + c*CK)*CONVD + h*HD;
    int p = t & 63;
    int lw = t >> 6;
    #pragma unroll 8
    for (int k=0;k<64;k++){
      int l = 4*k + lw;
      float x = bf2f(xp[(size_t)l*CONVD + p]);
      s_xsT[p][l ^ ((p&7)<<3)] = f2bf(x * s_dt[l]);
    }
  }
  __syncthreads();

  ffrag acc[4][2];
  #pragma unroll
  for (int ps=0;ps<4;ps++)
    #pragma unroll
    for (int ns=0;ns<2;ns++){ acc[ps][ns][0]=0.f; acc[ps][ns][1]=0.f; acc[ps][ns][2]=0.f; acc[ps][ns][3]=0.f; }
  const unsigned short* btp = btg + (size_t)b*DSTATE*LSEQ + c*CK;
  #pragma unroll 2
  for (int ks=0; ks<8; ++ks){
    int lb = 32*ks + 8*g;
    float4 w0 = *(const float4*)&s_w[lb];
    float4 w1 = *(const float4*)&s_w[lb+4];
    bfrag bfr[2];
    #pragma unroll
    for (int ns=0; ns<2; ++ns){
      int n = 32*wv + 16*ns + cq;
      bfr[ns] = *(const bfrag*)(btp + (size_t)n*LSEQ + lb);
    }
    bfrag afr[4];
    #pragma unroll
    for (int ps=0; ps<4; ++ps){
      int p = 16*ps + cq;
      bfrag xv = *(const bfrag*)&s_xsT[p][lb ^ ((p&7)<<3)];
      float f[8];
      f[0]=bf2f((unsigned short)xv[0])*w0.x; f[1]=bf2f((unsigned short)xv[1])*w0.y;
      f[2]=bf2f((unsigned short)xv[2])*w0.z; f[3]=bf2f((unsigned short)xv[3])*w0.w;
      f[4]=bf2f((unsigned short)xv[4])*w1.x; f[5]=bf2f((unsigned short)xv[5])*w1.y;
      f[6]=bf2f((unsigned short)xv[6])*w1.z; f[7]=bf2f((unsigned short)xv[7])*w1.w;
      afr[ps] = pack8(f);
    }
    #pragma unroll
    for (int ps=0; ps<4; ++ps)
      #pragma unroll
      for (int ns=0; ns<2; ++ns)
        acc[ps][ns] = __builtin_amdgcn_mfma_f32_16x16x32_bf16(afr[ps], bfr[ns], acc[ps][ns], 0,0,0);
  }
  size_t sbase = ((size_t)((b*NCH + c)*NH + h))*HD*DSTATE;
  #pragma unroll
  for (int ps=0; ps<4; ++ps)
    #pragma unroll
    for (int ns=0; ns<2; ++ns)
      #pragma unroll
      for (int j=0; j<4; ++j){
        int p = 16*ps + 4*g + j, n = 32*wv + 16*ns + cq;
        states[sbase + (size_t)p*DSTATE + n] = f2bf(acc[ps][ns][j]);
      }
}

// ---------------- K3: inter-chunk state scan (in-place, split 8-way) ----------------
__global__ __launch_bounds__(256) void k_scan(unsigned short* __restrict__ states,
    const float* __restrict__ acsg2)
{
  int bid = blockIdx.x;                     // NB*NH*8
  int sub = bid & 7, h = (bid>>3) & 31, b = bid >> 8;
  int t = threadIdx.x;
  int e0 = sub*1024 + t*4;
  float c0=0.f, c1=0.f, c2=0.f, c3=0.f;
  for (int c=0;c<NCH;c++){
    float dec = exp2f(acsg2[((size_t)(b*NCH + c)*NH + h)*CK + (CK-1)]);
    size_t base = ((size_t)((b*NCH + c)*NH + h))*HD*DSTATE + e0;
    uint2 v = *(uint2*)&states[base];
    float u0 = blo(v.x), u1 = bhi(v.x), u2 = blo(v.y), u3 = bhi(v.y);
    uint2 w; w.x = pk2(c0,c1); w.y = pk2(c2,c3);
    *(uint2*)&states[base] = w;
    c0 = dec*c0 + u0; c1 = dec*c1 + u1; c2 = dec*c2 + u2; c3 = dec*c3 + u3;
  }
}

// ---------------- K4 (MFMA): Y = Y_diag + Y_off -> ybuf (bf16), per (b,chunk,h) ----------------
__global__ __launch_bounds__(256) void k_Y(const unsigned short* __restrict__ xconv,
   const float* __restrict__ dtv,
   const unsigned short* __restrict__ G,
   const unsigned short* __restrict__ states,
   const float* __restrict__ acsg2,
   unsigned short* __restrict__ ybuf)
{
  int bid = blockIdx.x;                     // NB*NCH*NH
  int h = bid & 31, c = (bid>>5)&15, b = bid>>9;
  int t = threadIdx.x, lane = t & 63, wv = t >> 6;
  int cq = lane & 15, g = lane >> 4;
  __shared__ float s_acs2[CK];
  __shared__ float s_dt[CK];
  __shared__ unsigned short s_xsT[64][256];  // [p][l], l XOR-swizzled

  s_acs2[t] = acsg2[((size_t)(b*NCH + c)*NH + h)*CK + t];
  s_dt[t] = dtv[(size_t)(b*NH + h)*LSEQ + c*CK + t];
  __syncthreads();
  {
    const unsigned short* xp = xconv + (size_t)(b*LSEQ + c*CK)*CONVD + h*HD;
    int p = t & 63;
    int lw = t >> 6;
    #pragma unroll 8
    for (int k=0;k<64;k++){
      int l = 4*k + lw;
      float x = bf2f(xp[(size_t)l*CONVD + p]);
      s_xsT[p][l ^ ((p&7)<<3)] = f2bf(x * s_dt[l]);
    }
  }
  __syncthreads();

  ffrag acc[4][4];
  #pragma unroll
  for (int ls=0;ls<4;ls++)
    #pragma unroll
    for (int ps=0;ps<4;ps++){ acc[ls][ps][0]=0.f; acc[ls][ps][1]=0.f; acc[ls][ps][2]=0.f; acc[ls][ps][3]=0.f; }
  float a2l[4];
  #pragma unroll
  for (int ls=0; ls<4; ++ls) a2l[ls] = s_acs2[64*wv + 16*ls + cq];

  // ---- part A: Y_diag (triangular over s) ----
  const unsigned short* gp = G + (size_t)(b*NCH + c)*CK*CK;
  int nks = 2*wv + 2;
  for (int ks=0; ks<nks; ++ks){
    int sb = 32*ks + 8*g;
    float4 e0 = *(const float4*)&s_acs2[sb];
    float4 e1 = *(const float4*)&s_acs2[sb+4];
    float a2s[8] = {e0.x,e0.y,e0.z,e0.w,e1.x,e1.y,e1.z,e1.w};
    bfrag bfr[4];
    #pragma unroll
    for (int ps=0; ps<4; ++ps){
      int p = 16*ps + cq;
      bfr[ps] = *(const bfrag*)&s_xsT[p][sb ^ ((p&7)<<3)];
    }
    bfrag afr[4];
    #pragma unroll
    for (int ls=0; ls<4; ++ls){
      int l = 64*wv + 16*ls + cq;
      bfrag gv = *(const bfrag*)(gp + (size_t)l*CK + sb);
      float f[8];
      #pragma unroll
      for (int i=0;i<8;i++){
        int s = sb + i;
        float cf = exp2f(a2l[ls] - a2s[i]);
        cf = (s <= l) ? cf : 0.f;
        f[i] = bf2f((unsigned short)gv[i]) * cf;
      }
      afr[ls] = pack8(f);
    }
    #pragma unroll
    for (int ls=0; ls<4; ++ls)
      #pragma unroll
      for (int ps=0; ps<4; ++ps)
        acc[ls][ps] = __builtin_amdgcn_mfma_f32_16x16x32_bf16(afr[ls], bfr[ps], acc[ls][ps], 0,0,0);
  }

  // ---- part B: Y_off = exp2(acs_l) * C_l . prev_state (K = 128 over n) ----
  {
    float el[4];
    #pragma unroll
    for (int ls=0; ls<4; ++ls) el[ls] = exp2f(a2l[ls]);
    const unsigned short* crow = xconv + (size_t)(b*LSEQ + c*CK)*CONVD + DINNER + DSTATE;
    const unsigned short* psb = states + ((size_t)((b*NCH + c)*NH + h))*HD*DSTATE;
    #pragma unroll
    for (int ks=0; ks<4; ++ks){
      int nb = 32*ks + 8*g;
      bfrag bfr[4];
      #pragma unroll
      for (int pp=0; pp<4; ++pp)
        bfr[pp] = *(const bfrag*)(psb + (size_t)(16*pp + cq)*DSTATE + nb);
      bfrag afr[4];
      #pragma unroll
      for (int ls=0; ls<4; ++ls){
        int l = 64*wv + 16*ls + cq;
        bfrag cv = *(const bfrag*)(crow + (size_t)l*CONVD + nb);
        float f[8];
        #pragma unroll
        for (int i=0;i<8;i++) f[i] = bf2f((unsigned short)cv[i]) * el[ls];
        afr[ls] = pack8(f);
      }
      #pragma unroll
      for (int ls=0; ls<4; ++ls)
        #pragma unroll
        for (int pp=0; pp<4; ++pp)
          acc[ls][pp] = __builtin_amdgcn_mfma_f32_16x16x32_bf16(afr[ls], bfr[pp], acc[ls][pp], 0,0,0);
    }
  }

  unsigned short* yrow = ybuf + (size_t)(b*LSEQ + c*CK)*DINNER + h*HD;
  #pragma unroll
  for (int ls=0; ls<4; ++ls)
    #pragma unroll
    for (int ps=0; ps<4; ++ps)
      #pragma unroll
      for (int j=0; j<4; ++j){
        int l = 64*wv + 16*ls + 4*g + j, p = 16*ps + cq;
        yrow[(size_t)l*DINNER + p] = f2bf(acc[ls][ps][j]);
      }
}

// ---------------- K5: + D*x, silu(z) gate, RMSNorm -> out (f32) ----------------
__global__ __launch_bounds__(256) void k_final(const float* __restrict__ zx,
  const unsigned short* __restrict__ xconv, const unsigned short* __restrict__ ybuf,
  const float* __restrict__ dpar, const float* __restrict__ nw,
  float* __restrict__ out)
{
  int row = blockIdx.x;                     // b*LSEQ + l
  int t = threadIdx.x;
  int d0 = 8*t;
  const float* zrow = zx + (size_t)row*DIN;
  const unsigned short* xrow = xconv + (size_t)row*CONVD;
  const unsigned short* yrow = ybuf + (size_t)row*DINNER;
  float vals[8];
  float ss = 0.f;
  uint4 yv = *(const uint4*)&yrow[d0];
  uint4 xv = *(const uint4*)&xrow[d0];
  float4 z0 = *(const float4*)&zrow[d0];
  float4 z1 = *(const float4*)&zrow[d0+4];
  float dp = dpar[d0 >> 6];
  float yf[8], xf[8];
  yf[0]=blo(yv.x); yf[1]=bhi(yv.x); yf[2]=blo(yv.y); yf[3]=bhi(yv.y);
  yf[4]=blo(yv.z); yf[5]=bhi(yv.z); yf[6]=blo(yv.w); yf[7]=bhi(yv.w);
  xf[0]=blo(xv.x); xf[1]=bhi(xv.x); xf[2]=blo(xv.y); xf[3]=bhi(xv.y);
  xf[4]=blo(xv.z); xf[5]=bhi(xv.z); xf[6]=blo(xv.w); xf[7]=bhi(xv.w);
  float zf[8] = {z0.x,z0.y,z0.z,z0.w,z1.x,z1.y,z1.z,z1.w};
  #pragma unroll
  for (int e=0;e<8;e++){
    float y = yf[e] + xf[e]*dp;
    float z = zf[e];
    y *= z / (1.f + __expf(-z));
    vals[e] = y;
    ss += y*y;
  }
  #pragma unroll
  for (int off=1; off<64; off<<=1) ss += __shfl_xor(ss, off, 64);
  __shared__ float red[4];
  if ((t & 63) == 0) red[t>>6] = ss;
  __syncthreads();
  float tot = red[0]+red[1]+red[2]+red[3];
  float rms = rsqrtf(tot * (1.f/(float)DINNER) + 1e-5f);
  float* orow = out + (size_t)row*DINNER;
  float4 w0 = *(const float4*)&nw[d0];
  float4 w1 = *(const float4*)&nw[d0+4];
  float4 o0, o1;
  o0.x = vals[0]*rms*w0.x; o0.y = vals[1]*rms*w0.y;
  o0.z = vals[2]*rms*w0.z; o0.w = vals[3]*rms*w0.w;
  o1.x = vals[4]*rms*w1.x; o1.y = vals[5]*rms*w1.y;
  o1.z = vals[6]*rms*w1.z; o1.w = vals[7]*rms*w1.w;
  *(float4*)&orow[d0] = o0;
  *(float4*)&orow[d0+4] = o1;
}

extern "C" void kernel_launch(void* const* d_in, const int* in_sizes, int n_in,
                              void* d_out, int out_size, void* d_ws, size_t ws_size,
                              hipStream_t stream)
{
  const float* zx   = (const float*)d_in[0];
  const float* cw   = (const float*)d_in[1];
  const float* cb   = (const float*)d_in[2];
  const float* dtb  = (const float*)d_in[3];
  const float* alog = (const float*)d_in[4];
  const float* dpar = (const float*)d_in[5];
  const float* nw   = (const float*)d_in[6];
  float* out = (float*)d_out;
  char* ws = (char*)d_ws;

  // ws layout (bytes):
  unsigned short* xconv  = (unsigned short*)(ws);             // 37,748,736
  unsigned short* btg    = (unsigned short*)(ws + 37748736);  //  2,097,152
  float*          dtv    = (float*)(ws + 39845888);           //  1,048,576
  float*          acsg2  = (float*)(ws + 40894464);           //  1,048,576
  unsigned short* states = (unsigned short*)(ws + 41943040);  // 16,777,216
  unsigned short* G      = (unsigned short*)(ws + 58720256);  //  4,194,304
  unsigned short* ybuf   = (unsigned short*)(ws + 62914560);  // 33,554,432
  // total 96,468,992 bytes

  hipLaunchKernelGGL(k_conv,   dim3(NB*64*9), dim3(256), 0, stream, zx, cw, cb, xconv);
  hipLaunchKernelGGL(k_dt,     dim3(1024),  dim3(256), 0, stream, zx, dtb, dtv);
  hipLaunchKernelGGL(k_tr,     dim3(NB*64), dim3(256), 0, stream, xconv, btg);
  hipLaunchKernelGGL(k_gmat,   dim3(NB*NCH*10), dim3(256), 0, stream, xconv, G);
  hipLaunchKernelGGL(k_states, dim3(NB*NCH*NH), dim3(256), 0, stream, xconv, btg, dtv, alog, states, acsg2);
  hipLaunchKernelGGL(k_scan,   dim3(NB*NH*8),  dim3(256), 0, stream, states, acsg2);
  hipLaunchKernelGGL(k_Y,      dim3(NB*NCH*NH), dim3(256), 0, stream, xconv, dtv, G, states, acsg2, ybuf);
  hipLaunchKernelGGL(k_final,  dim3(NB*LSEQ), dim3(256), 0, stream, zx, xconv, ybuf, dpar, nw, out);
}

// Round 6
// 327.208 us; speedup vs baseline: 2.2987x; 1.0481x over previous
//
#include <hip/hip_runtime.h>
#include <hip/hip_bf16.h>

#define NB 2
#define LSEQ 4096
#define DIN 4384
#define DINNER 2048
#define DSTATE 128
#define CONVD 2304
#define HD 64
#define NH 32
#define CK 256
#define NCH 16

typedef __attribute__((ext_vector_type(8))) short bfrag;
typedef __attribute__((ext_vector_type(4))) float ffrag;

__device__ __forceinline__ float bf2f(unsigned short u){ return __uint_as_float(((unsigned int)u)<<16); }
__device__ __forceinline__ unsigned short f2bf(float f){
  unsigned int u = __float_as_uint(f);
  unsigned int r = (u + 0x7fffu + ((u>>16)&1u)) >> 16;
  return (unsigned short)r;
}
__device__ __forceinline__ unsigned int pk2(float a, float b){
  return (unsigned)f2bf(a) | ((unsigned)f2bf(b) << 16);
}
__device__ __forceinline__ float blo(unsigned int u){ return __uint_as_float(u<<16); }
__device__ __forceinline__ float bhi(unsigned int u){ return __uint_as_float(u & 0xffff0000u); }
// HW packed f32->bf16 (RNE), 1 instr per 2 elems
__device__ __forceinline__ unsigned int cvtpk(float a, float b){
  unsigned int r;
  asm("v_cvt_pk_bf16_f32 %0, %1, %2" : "=v"(r) : "v"(a), "v"(b));
  return r;
}
__device__ __forceinline__ bfrag pack8c(const float* f){
  union { unsigned int u[4]; bfrag b; } r;
  r.u[0]=cvtpk(f[0],f[1]); r.u[1]=cvtpk(f[2],f[3]);
  r.u[2]=cvtpk(f[4],f[5]); r.u[3]=cvtpk(f[6],f[7]);
  return r.b;
}

// ---------------- K1: causal conv + silu -> xconv (bf16), sliding-window ----------------
__global__ __launch_bounds__(256) void k_conv(const float* __restrict__ zx,
    const float* __restrict__ cw, const float* __restrict__ cb,
    unsigned short* __restrict__ xconv)
{
  int bid = blockIdx.x;                     // NB * 64 * 9
  int ct = bid % 9;
  int rt = bid / 9;
  int b = rt >> 6, lt = rt & 63;
  int t = threadIdx.x;
  int q = t & 63, lg = t >> 6;
  int c0 = ct*256 + q*4;
  const float* colp = zx + (size_t)b*LSEQ*DIN + DINNER + c0;
  float4 w0 = *(const float4*)&cw[(c0+0)*4];
  float4 w1 = *(const float4*)&cw[(c0+1)*4];
  float4 w2 = *(const float4*)&cw[(c0+2)*4];
  float4 w3 = *(const float4*)&cw[(c0+3)*4];
  float4 bias = *(const float4*)&cb[c0];
  int l0 = lt*64 + lg*16;
  float4 win0, win1, win2, win3;
  win0 = (l0-3 >= 0) ? *(const float4*)(colp + (size_t)(l0-3)*DIN) : make_float4(0,0,0,0);
  win1 = (l0-2 >= 0) ? *(const float4*)(colp + (size_t)(l0-2)*DIN) : make_float4(0,0,0,0);
  win2 = (l0-1 >= 0) ? *(const float4*)(colp + (size_t)(l0-1)*DIN) : make_float4(0,0,0,0);
  unsigned short* op = xconv + (size_t)(b*LSEQ)*CONVD + c0;
  #pragma unroll 4
  for (int i=0;i<16;i++){
    int l = l0 + i;
    win3 = *(const float4*)(colp + (size_t)l*DIN);
    float o0 = bias.x + w0.x*win0.x + w0.y*win1.x + w0.z*win2.x + w0.w*win3.x;
    float o1 = bias.y + w1.x*win0.y + w1.y*win1.y + w1.z*win2.y + w1.w*win3.y;
    float o2 = bias.z + w2.x*win0.z + w2.y*win1.z + w2.z*win2.z + w2.w*win3.z;
    float o3 = bias.w + w3.x*win0.w + w3.y*win1.w + w3.z*win2.w + w3.w*win3.w;
    o0 = o0 / (1.f + __expf(-o0));
    o1 = o1 / (1.f + __expf(-o1));
    o2 = o2 / (1.f + __expf(-o2));
    o3 = o3 / (1.f + __expf(-o3));
    uint2 pk; pk.x = cvtpk(o0,o1); pk.y = cvtpk(o2,o3);
    *(uint2*)&op[(size_t)l*CONVD] = pk;
    win0 = win1; win1 = win2; win2 = win3;
  }
}

// ---------------- K_misc: gmat (0..319) | tr (320..447) | dt (448..1471) ----------------
__constant__ int g_lt[10] = {0,1,1,2,2,2,3,3,3,3};
__constant__ int g_st[10] = {0,0,1,0,1,2,0,1,2,3};
__global__ __launch_bounds__(256) void k_misc(const float* __restrict__ zx,
    const float* __restrict__ dtb,
    const unsigned short* __restrict__ xconv,
    float* __restrict__ dtv, unsigned short* __restrict__ btg,
    unsigned short* __restrict__ G)
{
  __shared__ unsigned short sT[128][72];
  int bid = blockIdx.x;
  int t = threadIdx.x;
  if (bid < 320){
    // ---- gmat: G[l][s] = sum_n C[l,n]*B[s,n], bf16 l-major, lower-tri tiles ----
    int pr = bid % 10;
    int cc = bid / 10;
    int c = cc & 15, b = cc >> 4;
    int lt = g_lt[pr], st = g_st[pr];
    int lane = t & 63, wv = t >> 6;
    int cq = lane & 15, g = lane >> 4;
    const unsigned short* base = xconv + (size_t)(b*LSEQ + c*CK)*CONVD;
    ffrag acc[4];
    #pragma unroll
    for (int ss=0; ss<4; ++ss){ acc[ss][0]=0.f; acc[ss][1]=0.f; acc[ss][2]=0.f; acc[ss][3]=0.f; }
    #pragma unroll
    for (int ks=0; ks<4; ++ks){
      int nb = 32*ks + 8*g;
      int l = lt*64 + 16*wv + cq;
      bfrag afr = *(const bfrag*)(base + (size_t)l*CONVD + DINNER + DSTATE + nb);
      #pragma unroll
      for (int ss=0; ss<4; ++ss){
        int s = st*64 + 16*ss + cq;
        bfrag bfr = *(const bfrag*)(base + (size_t)s*CONVD + DINNER + nb);
        acc[ss] = __builtin_amdgcn_mfma_f32_16x16x32_bf16(afr, bfr, acc[ss], 0,0,0);
      }
    }
    unsigned short* gp = G + (size_t)(b*NCH + c)*CK*CK;
    #pragma unroll
    for (int ss=0; ss<4; ++ss)
      #pragma unroll
      for (int j=0; j<4; ++j){
        int l = lt*64 + 16*wv + 4*g + j, s = st*64 + 16*ss + cq;
        gp[(size_t)l*CK + s] = f2bf(acc[ss][j]);
      }
  } else if (bid < 448){
    // ---- tr: B slice -> btg[b][n][L] ----
    int bid2 = bid - 320;
    int b = bid2 >> 6, tile = bid2 & 63;
    int l0 = tile * 64;
    #pragma unroll
    for (int k=0;k<32;k++){
      int idx = 256*k + t;
      int l = idx >> 7, n = idx & 127;
      sT[n][l] = xconv[(size_t)(b*LSEQ + l0 + l)*CONVD + DINNER + n];
    }
    __syncthreads();
    #pragma unroll
    for (int k=0;k<32;k++){
      int idx = 256*k + t;
      int n = idx >> 6, l = idx & 63;
      btg[(size_t)(b*DSTATE + n)*LSEQ + l0 + l] = sT[n][l];
    }
  } else {
    // ---- dt = clip(softplus(raw+bias),0,100), layout [b][h][L] ----
    int idx = (bid-448)*256 + t;            // NB*NH*LSEQ
    int l = idx & (LSEQ-1);
    int bh = idx >> 12;
    int h = bh & 31, b = bh >> 5;
    float x = zx[(size_t)(b*LSEQ + l)*DIN + DINNER + CONVD + h] + dtb[h];
    float sp = (x > 20.f) ? x : log1pf(__expf(x));
    dtv[idx] = fminf(sp, 100.f);
  }
}

// ---------------- K2b: acs scan + states(MFMA), per (b,chunk,h) ----------------
__global__ __launch_bounds__(256) void k_states(const unsigned short* __restrict__ xconv,
   const unsigned short* __restrict__ btg,
   const float* __restrict__ dtv, const float* __restrict__ alog,
   unsigned short* __restrict__ states,
   float* __restrict__ acsg2)
{
  int bid = blockIdx.x;                     // NB*NCH*NH
  int h = bid & 31, c = (bid>>5)&15, b = bid>>9;
  int t = threadIdx.x, lane = t & 63, wv = t >> 6;
  int cq = lane & 15, g = lane >> 4;
  __shared__ float s_w[CK];                 // dt[l]*exp2(a2last - acs[l])
  __shared__ float s_wt[4];
  __shared__ unsigned short s_xsT[64][256]; // [p][l], l XOR-swizzled by ((p&7)<<3)

  const float LOG2E = 1.44269504088896340736f;
  float dtl = dtv[(size_t)(b*NH + h)*LSEQ + c*CK + t];
  float a2 = dtl * (-__expf(alog[h])) * LOG2E;
  // wave-level inclusive scan + cross-wave offsets
  float sc = a2;
  #pragma unroll
  for (int off=1; off<64; off<<=1){
    float v = __shfl_up(sc, off, 64);
    if (lane >= off) sc += v;
  }
  if (lane == 63) s_wt[wv] = sc;
  __syncthreads();
  float offacc = 0.f;
  #pragma unroll
  for (int w2=0; w2<4; ++w2) offacc += (w2 < wv) ? s_wt[w2] : 0.f;
  float acs = sc + offacc;
  float tot = s_wt[0]+s_wt[1]+s_wt[2]+s_wt[3];
  s_w[t] = dtl * exp2f(tot - acs);
  acsg2[((size_t)(b*NCH + c)*NH + h)*CK + t] = acs;
  __syncthreads();
  // stage xs*w (x * dt * decay-to-end), transposed + swizzled
  {
    const unsigned short* xp = xconv + (size_t)(b*LSEQ + c*CK)*CONVD + h*HD;
    int p = t & 63, lw = t >> 6;
    int sw = (p&7)<<3;
    #pragma unroll 8
    for (int k=0;k<32;k++){
      int l = 8*k + 2*lw;
      float x0 = bf2f(xp[(size_t)l*CONVD + p]) * s_w[l];
      float x1 = bf2f(xp[(size_t)(l+1)*CONVD + p]) * s_w[l+1];
      *(unsigned int*)&s_xsT[p][l ^ sw] = cvtpk(x0, x1);
    }
  }
  __syncthreads();

  ffrag acc[4][2];
  #pragma unroll
  for (int ps=0;ps<4;ps++)
    #pragma unroll
    for (int ns=0;ns<2;ns++){ acc[ps][ns][0]=0.f; acc[ps][ns][1]=0.f; acc[ps][ns][2]=0.f; acc[ps][ns][3]=0.f; }
  const unsigned short* btp = btg + (size_t)b*DSTATE*LSEQ + c*CK;
  #pragma unroll 2
  for (int ks=0; ks<8; ++ks){
    int lb = 32*ks + 8*g;
    bfrag bfr[2];
    #pragma unroll
    for (int ns=0; ns<2; ++ns){
      int n = 32*wv + 16*ns + cq;
      bfr[ns] = *(const bfrag*)(btp + (size_t)n*LSEQ + lb);
    }
    #pragma unroll
    for (int ps=0; ps<4; ++ps){
      int p = 16*ps + cq;
      bfrag afr = *(const bfrag*)&s_xsT[p][lb ^ ((p&7)<<3)];
      #pragma unroll
      for (int ns=0; ns<2; ++ns)
        acc[ps][ns] = __builtin_amdgcn_mfma_f32_16x16x32_bf16(afr, bfr[ns], acc[ps][ns], 0,0,0);
    }
  }
  size_t sbase = ((size_t)((b*NCH + c)*NH + h))*HD*DSTATE;
  #pragma unroll
  for (int ps=0; ps<4; ++ps)
    #pragma unroll
    for (int ns=0; ns<2; ++ns)
      #pragma unroll
      for (int j=0; j<4; ++j){
        int p = 16*ps + 4*g + j, n = 32*wv + 16*ns + cq;
        states[sbase + (size_t)p*DSTATE + n] = f2bf(acc[ps][ns][j]);
      }
}

// ---------------- K3: inter-chunk state scan (in-place, split 8-way) ----------------
__global__ __launch_bounds__(256) void k_scan(unsigned short* __restrict__ states,
    const float* __restrict__ acsg2)
{
  int bid = blockIdx.x;                     // NB*NH*8
  int sub = bid & 7, h = (bid>>3) & 31, b = bid >> 8;
  int t = threadIdx.x;
  int e0 = sub*1024 + t*4;
  float c0=0.f, c1=0.f, c2=0.f, c3=0.f;
  for (int c=0;c<NCH;c++){
    float dec = exp2f(acsg2[((size_t)(b*NCH + c)*NH + h)*CK + (CK-1)]);
    size_t base = ((size_t)((b*NCH + c)*NH + h))*HD*DSTATE + e0;
    uint2 v = *(uint2*)&states[base];
    float u0 = blo(v.x), u1 = bhi(v.x), u2 = blo(v.y), u3 = bhi(v.y);
    uint2 w; w.x = cvtpk(c0,c1); w.y = cvtpk(c2,c3);
    *(uint2*)&states[base] = w;
    c0 = dec*c0 + u0; c1 = dec*c1 + u1; c2 = dec*c2 + u2; c3 = dec*c3 + u3;
  }
}

// ---------------- K4 (MFMA): Y = Y_off + Y_diag -> ybuf (bf16), per (b,chunk,h) ----------------
__global__ __launch_bounds__(256) void k_Y(const unsigned short* __restrict__ xconv,
   const float* __restrict__ dtv,
   const unsigned short* __restrict__ G,
   const unsigned short* __restrict__ states,
   const float* __restrict__ acsg2,
   unsigned short* __restrict__ ybuf)
{
  int bid = blockIdx.x;                     // NB*NCH*NH
  int h = bid & 31, c = (bid>>5)&15, b = bid>>9;
  int t = threadIdx.x, lane = t & 63, wv = t >> 6;
  int cq = lane & 15, g = lane >> 4;
  __shared__ float s_acs2[CK];
  __shared__ float s_dt[CK];
  __shared__ unsigned short s_xsT[64][256];

  s_acs2[t] = acsg2[((size_t)(b*NCH + c)*NH + h)*CK + t];
  s_dt[t] = dtv[(size_t)(b*NH + h)*LSEQ + c*CK + t];
  __syncthreads();
  {
    const unsigned short* xp = xconv + (size_t)(b*LSEQ + c*CK)*CONVD + h*HD;
    int p = t & 63, lw = t >> 6;
    int sw = (p&7)<<3;
    #pragma unroll 8
    for (int k=0;k<32;k++){
      int l = 8*k + 2*lw;
      float x0 = bf2f(xp[(size_t)l*CONVD + p]) * s_dt[l];
      float x1 = bf2f(xp[(size_t)(l+1)*CONVD + p]) * s_dt[l+1];
      *(unsigned int*)&s_xsT[p][l ^ sw] = cvtpk(x0, x1);
    }
  }
  __syncthreads();

  ffrag acc[4][4];
  #pragma unroll
  for (int ls=0;ls<4;ls++)
    #pragma unroll
    for (int ps=0;ps<4;ps++){ acc[ls][ps][0]=0.f; acc[ls][ps][1]=0.f; acc[ls][ps][2]=0.f; acc[ls][ps][3]=0.f; }

  // ---- part B FIRST: acc = C . prev_state (raw fragments, no packing) ----
  {
    const unsigned short* crow = xconv + (size_t)(b*LSEQ + c*CK)*CONVD + DINNER + DSTATE;
    const unsigned short* psb = states + ((size_t)((b*NCH + c)*NH + h))*HD*DSTATE;
    #pragma unroll
    for (int ks=0; ks<4; ++ks){
      int nb = 32*ks + 8*g;
      bfrag bfr[4];
      #pragma unroll
      for (int pp=0; pp<4; ++pp)
        bfr[pp] = *(const bfrag*)(psb + (size_t)(16*pp + cq)*DSTATE + nb);
      #pragma unroll
      for (int ls=0; ls<4; ++ls){
        int l = 64*wv + 16*ls + cq;
        bfrag afr = *(const bfrag*)(crow + (size_t)l*CONVD + nb);
        #pragma unroll
        for (int pp=0; pp<4; ++pp)
          acc[ls][pp] = __builtin_amdgcn_mfma_f32_16x16x32_bf16(afr, bfr[pp], acc[ls][pp], 0,0,0);
      }
    }
    // scale by exp2(acs_l) in f32 (el <= 1)
    #pragma unroll
    for (int ls=0; ls<4; ++ls)
      #pragma unroll
      for (int j=0; j<4; ++j){
        float el = exp2f(s_acs2[64*wv + 16*ls + 4*g + j]);
        #pragma unroll
        for (int ps=0; ps<4; ++ps) acc[ls][ps][j] *= el;
      }
  }

  // ---- part A: Y_diag, decay via anchored downward chain ----
  float a2l[4];
  #pragma unroll
  for (int ls=0; ls<4; ++ls) a2l[ls] = s_acs2[64*wv + 16*ls + cq];
  const unsigned short* gp = G + (size_t)(b*NCH + c)*CK*CK;
  int nks = 2*wv + 2;
  for (int ks=0; ks<nks; ++ks){
    int sb = 32*ks + 8*g;
    float4 e0 = *(const float4*)&s_acs2[sb];
    float4 e1 = *(const float4*)&s_acs2[sb+4];
    float a2s[8] = {e0.x,e0.y,e0.z,e0.w,e1.x,e1.y,e1.z,e1.w};
    // step-down ratios (<=1): ddn[i] = exp2(a2s[i]-a2s[i-1]), i=1..7
    float ddn[8];
    #pragma unroll
    for (int i=1;i<8;i++) ddn[i] = exp2f(a2s[i] - a2s[i-1]);
    bfrag bfrx[4];
    #pragma unroll
    for (int ps=0; ps<4; ++ps){
      int p = 16*ps + cq;
      bfrx[ps] = *(const bfrag*)&s_xsT[p][sb ^ ((p&7)<<3)];
    }
    bfrag afr[4];
    #pragma unroll
    for (int ls=0; ls<4; ++ls){
      int l = 64*wv + 16*ls + cq;
      int di = l - sb;
      int astar = (di < 7) ? di : 7;
      float aval = exp2f(a2l[ls] - s_acs2[sb + astar]);  // arg<=0 when di>=0; di<0 unused
      bfrag gv = *(const bfrag*)(gp + (size_t)l*CK + sb);
      float run = 0.f;
      float ff[8];
      #pragma unroll
      for (int i=7;i>=0;--i){
        run = (i == astar) ? aval : run;
        ff[i] = bf2f((unsigned short)gv[i]) * run;
        if (i) run *= ddn[i];
      }
      afr[ls] = pack8c(ff);
    }
    #pragma unroll
    for (int ls=0; ls<4; ++ls)
      #pragma unroll
      for (int ps=0; ps<4; ++ps)
        acc[ls][ps] = __builtin_amdgcn_mfma_f32_16x16x32_bf16(afr[ls], bfrx[ps], acc[ls][ps], 0,0,0);
  }

  unsigned short* yrow = ybuf + (size_t)(b*LSEQ + c*CK)*DINNER + h*HD;
  #pragma unroll
  for (int ls=0; ls<4; ++ls)
    #pragma unroll
    for (int ps=0; ps<4; ++ps)
      #pragma unroll
      for (int j=0; j<4; ++j){
        int l = 64*wv + 16*ls + 4*g + j, p = 16*ps + cq;
        yrow[(size_t)l*DINNER + p] = f2bf(acc[ls][ps][j]);
      }
}

// ---------------- K5: + D*x, silu(z) gate, RMSNorm -> out (f32) ----------------
__global__ __launch_bounds__(256) void k_final(const float* __restrict__ zx,
  const unsigned short* __restrict__ xconv, const unsigned short* __restrict__ ybuf,
  const float* __restrict__ dpar, const float* __restrict__ nw,
  float* __restrict__ out)
{
  int row = blockIdx.x;                     // b*LSEQ + l
  int t = threadIdx.x;
  int d0 = 8*t;
  const float* zrow = zx + (size_t)row*DIN;
  const unsigned short* xrow = xconv + (size_t)row*CONVD;
  const unsigned short* yrow = ybuf + (size_t)row*DINNER;
  float vals[8];
  float ss = 0.f;
  uint4 yv = *(const uint4*)&yrow[d0];
  uint4 xv = *(const uint4*)&xrow[d0];
  float4 z0 = *(const float4*)&zrow[d0];
  float4 z1 = *(const float4*)&zrow[d0+4];
  float dp = dpar[d0 >> 6];
  float yf[8], xf[8];
  yf[0]=blo(yv.x); yf[1]=bhi(yv.x); yf[2]=blo(yv.y); yf[3]=bhi(yv.y);
  yf[4]=blo(yv.z); yf[5]=bhi(yv.z); yf[6]=blo(yv.w); yf[7]=bhi(yv.w);
  xf[0]=blo(xv.x); xf[1]=bhi(xv.x); xf[2]=blo(xv.y); xf[3]=bhi(xv.y);
  xf[4]=blo(xv.z); xf[5]=bhi(xv.z); xf[6]=blo(xv.w); xf[7]=bhi(xv.w);
  float zf[8] = {z0.x,z0.y,z0.z,z0.w,z1.x,z1.y,z1.z,z1.w};
  #pragma unroll
  for (int e=0;e<8;e++){
    float y = yf[e] + xf[e]*dp;
    float z = zf[e];
    y *= z / (1.f + __expf(-z));
    vals[e] = y;
    ss += y*y;
  }
  #pragma unroll
  for (int off=1; off<64; off<<=1) ss += __shfl_xor(ss, off, 64);
  __shared__ float red[4];
  if ((t & 63) == 0) red[t>>6] = ss;
  __syncthreads();
  float tot = red[0]+red[1]+red[2]+red[3];
  float rms = rsqrtf(tot * (1.f/(float)DINNER) + 1e-5f);
  float* orow = out + (size_t)row*DINNER;
  float4 w0 = *(const float4*)&nw[d0];
  float4 w1 = *(const float4*)&nw[d0+4];
  float4 o0, o1;
  o0.x = vals[0]*rms*w0.x; o0.y = vals[1]*rms*w0.y;
  o0.z = vals[2]*rms*w0.z; o0.w = vals[3]*rms*w0.w;
  o1.x = vals[4]*rms*w1.x; o1.y = vals[5]*rms*w1.y;
  o1.z = vals[6]*rms*w1.z; o1.w = vals[7]*rms*w1.w;
  *(float4*)&orow[d0] = o0;
  *(float4*)&orow[d0+4] = o1;
}

extern "C" void kernel_launch(void* const* d_in, const int* in_sizes, int n_in,
                              void* d_out, int out_size, void* d_ws, size_t ws_size,
                              hipStream_t stream)
{
  const float* zx   = (const float*)d_in[0];
  const float* cw   = (const float*)d_in[1];
  const float* cb   = (const float*)d_in[2];
  const float* dtb  = (const float*)d_in[3];
  const float* alog = (const float*)d_in[4];
  const float* dpar = (const float*)d_in[5];
  const float* nw   = (const float*)d_in[6];
  float* out = (float*)d_out;
  char* ws = (char*)d_ws;

  // ws layout (bytes):
  unsigned short* xconv  = (unsigned short*)(ws);             // 37,748,736
  unsigned short* btg    = (unsigned short*)(ws + 37748736);  //  2,097,152
  float*          dtv    = (float*)(ws + 39845888);           //  1,048,576
  float*          acsg2  = (float*)(ws + 40894464);           //  1,048,576
  unsigned short* states = (unsigned short*)(ws + 41943040);  // 16,777,216
  unsigned short* G      = (unsigned short*)(ws + 58720256);  //  4,194,304
  unsigned short* ybuf   = (unsigned short*)(ws + 62914560);  // 33,554,432
  // total 96,468,992 bytes

  hipLaunchKernelGGL(k_conv,   dim3(NB*64*9), dim3(256), 0, stream, zx, cw, cb, xconv);
  hipLaunchKernelGGL(k_misc,   dim3(1472), dim3(256), 0, stream, zx, dtb, xconv, dtv, btg, G);
  hipLaunchKernelGGL(k_states, dim3(NB*NCH*NH), dim3(256), 0, stream, xconv, btg, dtv, alog, states, acsg2);
  hipLaunchKernelGGL(k_scan,   dim3(NB*NH*8),  dim3(256), 0, stream, states, acsg2);
  hipLaunchKernelGGL(k_Y,      dim3(NB*NCH*NH), dim3(256), 0, stream, xconv, dtv, G, states, acsg2, ybuf);
  hipLaunchKernelGGL(k_final,  dim3(NB*LSEQ), dim3(256), 0, stream, zx, xconv, ybuf, dpar, nw, out);
}